// Round 3
// baseline (1216.526 us; speedup 1.0000x reference)
//
#include <hip/hip_runtime.h>
#include <hip/hip_bf16.h>
#include <math.h>

#define N_NODES 30000
#define M_P     4
#define E_EDGES 480000
#define N_TOK   (N_NODES * 4)
#define N_ROWS  (M_P * N_NODES)      // 120000 (m,src) rows
#define LN_EPS  1e-5f

typedef short bf16x8 __attribute__((ext_vector_type(8)));
typedef float f32x4  __attribute__((ext_vector_type(4)));
#define MFMA_B16(a, b, c) __builtin_amdgcn_mfma_f32_16x16x32_bf16(a, b, c, 0, 0, 0)

__device__ inline unsigned short f2bf(float f) {
    union { float f; unsigned u; } v; v.f = f;
    unsigned r = v.u + 0x7fffu + ((v.u >> 16) & 1u);
    return (unsigned short)(r >> 16);
}
__device__ inline unsigned pack2bf(float a, float b) {
    return (unsigned)f2bf(a) | ((unsigned)f2bf(b) << 16);
}

// ===================== Kernel 1: y = x@Wl^T ; z = x@(W0+W1)^T + (b0+b1+bl) =====================
__global__ __launch_bounds__(256, 2) void k_lin_yz(
    const float* __restrict__ x,
    const float* __restrict__ W0, const float* __restrict__ b0,
    const float* __restrict__ Wl, const float* __restrict__ bl,
    const float* __restrict__ W1, const float* __restrict__ b1,
    float* __restrict__ y, float* __restrict__ z)
{
    __shared__ float xT[128][68];   // [k][node]
    __shared__ float wT[128][68];   // [k][h]
    const int t     = threadIdx.x;
    const int m     = blockIdx.y >> 1;
    const int which = blockIdx.y & 1;
    const int node0 = blockIdx.x * 64;

    #pragma unroll
    for (int i = 0; i < 8; ++i) {
        const int node = (t & 31) + 32 * (i & 1);
        const int kq   = (t >> 5) + 8 * (i >> 1);
        float4 v = make_float4(0.f, 0.f, 0.f, 0.f);
        const int n = node0 + node;
        if (n < N_NODES) v = *(const float4*)(x + n * 128 + kq * 4);
        xT[kq * 4 + 0][node] = v.x; xT[kq * 4 + 1][node] = v.y;
        xT[kq * 4 + 2][node] = v.z; xT[kq * 4 + 3][node] = v.w;
    }
    #pragma unroll
    for (int i = 0; i < 8; ++i) {
        const int h  = (t & 31) + 32 * (i & 1);
        const int kq = (t >> 5) + 8 * (i >> 1);
        float4 v;
        if (which) {
            v = *(const float4*)(W0 + (m * 64 + h) * 128 + kq * 4);
            const float4 v2 = *(const float4*)(W1 + (m * 64 + h) * 128 + kq * 4);
            v.x += v2.x; v.y += v2.y; v.z += v2.z; v.w += v2.w;
        } else {
            v = *(const float4*)(Wl + (m * 64 + h) * 128 + kq * 4);
        }
        wT[kq * 4 + 0][h] = v.x; wT[kq * 4 + 1][h] = v.y;
        wT[kq * 4 + 2][h] = v.z; wT[kq * 4 + 3][h] = v.w;
    }
    __syncthreads();

    const int tx = t & 15, ty = t >> 4;
    const int hb = tx * 4, nb = ty * 4;
    float acc[4][4] = {};
    #pragma unroll 8
    for (int k = 0; k < 128; ++k) {
        const float4 a = *(const float4*)&xT[k][nb];
        const float4 b = *(const float4*)&wT[k][hb];
        acc[0][0] += a.x * b.x; acc[0][1] += a.x * b.y; acc[0][2] += a.x * b.z; acc[0][3] += a.x * b.w;
        acc[1][0] += a.y * b.x; acc[1][1] += a.y * b.y; acc[1][2] += a.y * b.z; acc[1][3] += a.y * b.w;
        acc[2][0] += a.z * b.x; acc[2][1] += a.z * b.y; acc[2][2] += a.z * b.z; acc[2][3] += a.z * b.w;
        acc[3][0] += a.w * b.x; acc[3][1] += a.w * b.y; acc[3][2] += a.w * b.z; acc[3][3] += a.w * b.w;
    }
    float bias[4] = {0.f, 0.f, 0.f, 0.f};
    if (which) {
        #pragma unroll
        for (int j = 0; j < 4; ++j)
            bias[j] = b0[m * 64 + hb + j] + b1[m * 64 + hb + j] + bl[m * 64 + hb + j];
    }
    float* outp = which ? z : y;
    #pragma unroll
    for (int i = 0; i < 4; ++i) {
        const int n = node0 + nb + i;
        if (n < N_NODES) {
            float4 v = make_float4(acc[i][0] + bias[0], acc[i][1] + bias[1],
                                   acc[i][2] + bias[2], acc[i][3] + bias[3]);
            *(float4*)(outp + (m * N_NODES + n) * 64 + hb) = v;
        }
    }
}

// ===================== Scatter replacement: bin-and-gather (no fp32 atomics) =====================
// Phase 1: histogram of src per (m, src) row
__global__ __launch_bounds__(256) void k_hist(
    const int* __restrict__ ei, int* __restrict__ cnt)
{
    const int g = blockIdx.x * 256 + threadIdx.x;       // < M*E
    const int m = g / E_EDGES;
    const int e = g - m * E_EDGES;
    const int src = ei[(m * 2) * E_EDGES + e];
    atomicAdd(&cnt[m * N_NODES + src], 1);
}

// Phase 2: exclusive scan of 120000 counts (single block, 1024 threads, 16 waves)
__global__ __launch_bounds__(1024) void k_scan(
    const int* __restrict__ cnt, int* __restrict__ off)
{
    __shared__ int wsum[16];
    const int t = threadIdx.x, lane = t & 63, w = t >> 6;
    int run = 0;
    for (int base = 0; base < N_ROWS; base += 1024) {
        __syncthreads();                 // protect wsum from prior iteration's readers
        const int i = base + t;
        const int v = (i < N_ROWS) ? cnt[i] : 0;
        int s = v;
        #pragma unroll
        for (int d = 1; d < 64; d <<= 1) {
            const int u = __shfl_up(s, d);
            if (lane >= d) s += u;
        }
        if (lane == 63) wsum[w] = s;
        __syncthreads();
        if (w == 0 && lane < 16) {
            int ws = wsum[lane];
            #pragma unroll
            for (int d = 1; d < 16; d <<= 1) {
                const int u = __shfl_up(ws, d);
                if (lane >= d) ws += u;
            }
            wsum[lane] = ws;
        }
        __syncthreads();
        const int wprev = (w == 0) ? 0 : wsum[w - 1];
        if (i < N_ROWS) off[i] = run + wprev + s - v;
        run += wsum[15];
    }
    if (t == 0) off[N_ROWS] = run;
}

// Phase 3: fill bins — binned[pos] = global y-row index of dst
__global__ __launch_bounds__(256) void k_fill(
    const int* __restrict__ ei, int* __restrict__ cur, int* __restrict__ binned)
{
    const int g = blockIdx.x * 256 + threadIdx.x;       // < M*E
    const int m = g / E_EDGES;
    const int e = g - m * E_EDGES;
    const int src = ei[(m * 2) * E_EDGES + e];
    const int dst = ei[(m * 2 + 1) * E_EDGES + e];
    const int pos = atomicAdd(&cur[m * N_NODES + src], 1);
    binned[pos] = m * N_NODES + dst;
}

// Phase 4: gather-reduce — one wave per (m,src) row; lane = feature
__global__ __launch_bounds__(256) void k_gather(
    const int* __restrict__ off, const int* __restrict__ binned,
    const float* __restrict__ y, float* __restrict__ aggh)
{
    const int w = threadIdx.x >> 6, lane = threadIdx.x & 63;
    const int row = blockIdx.x * 4 + w;                 // < N_ROWS
    const int beg = off[row], end = off[row + 1];
    float acc = 0.f;
    for (int i = beg; i < end; i += 64) {
        int idx = 0;
        if (i + lane < end) idx = binned[i + lane];     // coalesced, 1 load / 64 edges
        const int cn = min(64, end - i);
        for (int j = 0; j < cn; ++j) {
            const int r = __shfl(idx, j);               // broadcast row index
            acc += y[r * 64 + lane];                    // 256 B contiguous, L3-resident
        }
    }
    aggh[row * 64 + lane] = acc;
}

// ===================== Kernel 3: e[n][m][:] = (relu(aggh+z) @ Wo^T + bo) * mpw[m] =====================
__global__ __launch_bounds__(256) void k_emb(
    const float* __restrict__ aggh, const float* __restrict__ z,
    const float* __restrict__ Wo, const float* __restrict__ bo,
    const float* __restrict__ mpw, float* __restrict__ e)
{
    __shared__ float hT[64][20];
    __shared__ float WoT[64][64];
    const int t = threadIdx.x;
    const int node0 = blockIdx.x * 16;

    for (int m = 0; m < 4; ++m) {
        #pragma unroll
        for (int i = 0; i < 4; ++i) {
            const int o  = (t & 15) + 16 * i;
            const int kq = t >> 4;
            const float4 v = *(const float4*)(Wo + (m * 64 + o) * 64 + kq * 4);
            WoT[kq * 4 + 0][o] = v.x; WoT[kq * 4 + 1][o] = v.y;
            WoT[kq * 4 + 2][o] = v.z; WoT[kq * 4 + 3][o] = v.w;
        }
        {
            const int node = t & 15, kq = t >> 4;
            const int n = node0 + node;
            const float4 a = *(const float4*)(aggh + (m * N_NODES + n) * 64 + kq * 4);
            const float4 b = *(const float4*)(z + (m * N_NODES + n) * 64 + kq * 4);
            hT[kq * 4 + 0][node] = fmaxf(a.x + b.x, 0.f);
            hT[kq * 4 + 1][node] = fmaxf(a.y + b.y, 0.f);
            hT[kq * 4 + 2][node] = fmaxf(a.z + b.z, 0.f);
            hT[kq * 4 + 3][node] = fmaxf(a.w + b.w, 0.f);
        }
        __syncthreads();
        const int o = t & 63, nl4 = (t >> 6) * 4;
        float acc[4] = {};
        #pragma unroll 8
        for (int k = 0; k < 64; ++k) {
            const float bw = WoT[k][o];
            const float4 a = *(const float4*)&hT[k][nl4];
            acc[0] += a.x * bw; acc[1] += a.y * bw; acc[2] += a.z * bw; acc[3] += a.w * bw;
        }
        const float bb = bo[m * 64 + o];
        const float w  = mpw[m];
        #pragma unroll
        for (int i = 0; i < 4; ++i)
            e[((node0 + nl4 + i) * 4 + m) * 64 + o] = (acc[i] + bb) * w;
        __syncthreads();
    }
}

// ===================== Kernel 4: attention block =====================
__global__ __launch_bounds__(256) void k_attn(
    const float* __restrict__ ein,
    const float* __restrict__ tinw, const float* __restrict__ tinb,
    const float* __restrict__ tow, const float* __restrict__ tob,
    const float* __restrict__ ln1g, const float* __restrict__ ln1b,
    float* __restrict__ eout, int l)
{
    __shared__ float eT[64][33];
    __shared__ float wqkvT[64][192];
    __shared__ float qkvs[32][200];
    __shared__ float oT[64][32];
    __shared__ float towT[64][64];
    const int t = threadIdx.x;
    const int tok0 = blockIdx.x * 32;

    #pragma unroll
    for (int i = 0; i < 12; ++i) {
        const int j  = (t & 15) + 16 * i;
        const int kq = t >> 4;
        const float4 v = *(const float4*)(tinw + (l * 192 + j) * 64 + kq * 4);
        wqkvT[kq * 4 + 0][j] = v.x; wqkvT[kq * 4 + 1][j] = v.y;
        wqkvT[kq * 4 + 2][j] = v.z; wqkvT[kq * 4 + 3][j] = v.w;
    }
    #pragma unroll
    for (int i = 0; i < 4; ++i) {
        const int o  = (t & 15) + 16 * i;
        const int kq = t >> 4;
        const float4 v = *(const float4*)(tow + (l * 64 + o) * 64 + kq * 4);
        towT[kq * 4 + 0][o] = v.x; towT[kq * 4 + 1][o] = v.y;
        towT[kq * 4 + 2][o] = v.z; towT[kq * 4 + 3][o] = v.w;
    }
    #pragma unroll
    for (int i = 0; i < 2; ++i) {
        const int tok = t & 31;
        const int kq  = (t >> 5) + 8 * i;
        const float4 v = *(const float4*)(ein + (tok0 + tok) * 64 + kq * 4);
        eT[kq * 4 + 0][tok] = v.x; eT[kq * 4 + 1][tok] = v.y;
        eT[kq * 4 + 2][tok] = v.z; eT[kq * 4 + 3][tok] = v.w;
    }
    __syncthreads();

    {
        const int tx = t & 15, ty = t >> 4;
        const int j0 = tx * 12, tk0 = ty * 2;
        float acc0[12], acc1[12];
        #pragma unroll
        for (int jj = 0; jj < 12; ++jj) {
            const float b = tinb[l * 192 + j0 + jj];
            acc0[jj] = b; acc1[jj] = b;
        }
        #pragma unroll 4
        for (int k = 0; k < 64; ++k) {
            const float a0 = eT[k][tk0], a1 = eT[k][tk0 + 1];
            const float4 b0 = *(const float4*)&wqkvT[k][j0];
            const float4 b1 = *(const float4*)&wqkvT[k][j0 + 4];
            const float4 b2 = *(const float4*)&wqkvT[k][j0 + 8];
            const float bb[12] = {b0.x, b0.y, b0.z, b0.w, b1.x, b1.y, b1.z, b1.w, b2.x, b2.y, b2.z, b2.w};
            #pragma unroll
            for (int jj = 0; jj < 12; ++jj) { acc0[jj] += a0 * bb[jj]; acc1[jj] += a1 * bb[jj]; }
        }
        #pragma unroll
        for (int jj = 0; jj < 12; ++jj) {
            qkvs[tk0][j0 + jj]     = acc0[jj];
            qkvs[tk0 + 1][j0 + jj] = acc1[jj];
        }
    }
    __syncthreads();

    if (t < 64) {
        const int node = t >> 3, head = t & 7;
        const int tb = node * 4;
        const int qo = head * 8, ko = 64 + head * 8, vo = 128 + head * 8;
        float kk[4][8], vv[4][8];
        #pragma unroll
        for (int j = 0; j < 4; ++j)
            #pragma unroll
            for (int d = 0; d < 8; ++d) { kk[j][d] = qkvs[tb + j][ko + d]; vv[j][d] = qkvs[tb + j][vo + d]; }
        const float scale = 0.35355339059327373f;
        #pragma unroll
        for (int i = 0; i < 4; ++i) {
            float q[8];
            #pragma unroll
            for (int d = 0; d < 8; ++d) q[d] = qkvs[tb + i][qo + d];
            float s[4];
            #pragma unroll
            for (int j = 0; j < 4; ++j) {
                float acc = 0.f;
                #pragma unroll
                for (int d = 0; d < 8; ++d) acc += q[d] * kk[j][d];
                s[j] = acc * scale;
            }
            const float mx = fmaxf(fmaxf(s[0], s[1]), fmaxf(s[2], s[3]));
            float p[4], sum = 0.f;
            #pragma unroll
            for (int j = 0; j < 4; ++j) { p[j] = __expf(s[j] - mx); sum += p[j]; }
            const float inv = 1.f / sum;
            #pragma unroll
            for (int d = 0; d < 8; ++d)
                oT[qo + d][tb + i] = (p[0] * vv[0][d] + p[1] * vv[1][d] + p[2] * vv[2][d] + p[3] * vv[3][d]) * inv;
        }
    }
    __syncthreads();

    {
        const int tx = t & 31, ty = t >> 5;
        const int o0 = tx * 2, tk0 = ty * 4;
        float acc[4][2] = {};
        #pragma unroll 4
        for (int k = 0; k < 64; ++k) {
            const float4 a = *(const float4*)&oT[k][tk0];
            const float b0 = towT[k][o0], b1 = towT[k][o0 + 1];
            acc[0][0] += a.x * b0; acc[0][1] += a.x * b1;
            acc[1][0] += a.y * b0; acc[1][1] += a.y * b1;
            acc[2][0] += a.z * b0; acc[2][1] += a.z * b1;
            acc[3][0] += a.w * b0; acc[3][1] += a.w * b1;
        }
        const float g0 = ln1g[l * 64 + o0], g1 = ln1g[l * 64 + o0 + 1];
        const float be0 = ln1b[l * 64 + o0], be1 = ln1b[l * 64 + o0 + 1];
        const float tb0 = tob[l * 64 + o0], tb1 = tob[l * 64 + o0 + 1];
        #pragma unroll
        for (int i = 0; i < 4; ++i) {
            float v0 = acc[i][0] + tb0 + eT[o0][tk0 + i];
            float v1 = acc[i][1] + tb1 + eT[o0 + 1][tk0 + i];
            float s = v0 + v1;
            s += __shfl_xor(s, 1); s += __shfl_xor(s, 2); s += __shfl_xor(s, 4);
            s += __shfl_xor(s, 8); s += __shfl_xor(s, 16);
            const float mean = s * (1.f / 64.f);
            const float d0 = v0 - mean, d1 = v1 - mean;
            float vs = d0 * d0 + d1 * d1;
            vs += __shfl_xor(vs, 1); vs += __shfl_xor(vs, 2); vs += __shfl_xor(vs, 4);
            vs += __shfl_xor(vs, 8); vs += __shfl_xor(vs, 16);
            const float r = rsqrtf(vs * (1.f / 64.f) + LN_EPS);
            const int tok = tok0 + tk0 + i;
            float2 w2 = make_float2(d0 * r * g0 + be0, d1 * r * g1 + be1);
            *(float2*)(eout + tok * 64 + o0) = w2;
        }
    }
}

// ===================== Kernel 4.5: pre-shuffle FFN weights to MFMA-fragment-major bf16 =====================
__global__ __launch_bounds__(256) void k_wshuf(
    const float* __restrict__ ff1w, const float* __restrict__ ff2w,
    unsigned short* __restrict__ w1s, unsigned short* __restrict__ w2s)
{
    const int g = blockIdx.x * 256 + threadIdx.x;   // [0, 262144)
    {
        const int l = g >> 17, r2 = g & 131071;
        const int f = r2 >> 6, k = r2 & 63;
        const int c = f >> 6, fc = f & 63, ft = fc >> 4, m = fc & 15;
        const int h = k >> 5, q = (k >> 3) & 3, j = k & 7;
        w1s[l * 131072 + c * 4096 + (ft * 2 + h) * 512 + (q * 16 + m) * 8 + j] = f2bf(ff1w[g]);
    }
    {
        const int l = g >> 17, r2 = g & 131071;
        const int o = r2 >> 11, f = r2 & 2047;
        const int c = f >> 6, fc = f & 63, h = fc >> 5, q = (fc >> 3) & 3, j = fc & 7;
        const int ot = o >> 4, m = o & 15;
        w2s[l * 131072 + c * 4096 + (ot * 2 + h) * 512 + (q * 16 + m) * 8 + j] = f2bf(ff2w[g]);
    }
}

// ===================== Kernel 5: FFN via bf16 MFMA (fused relu-MLP + residual + LN2) =====================
__global__ __launch_bounds__(256, 2) void k_ffn_mfma(
    const float* __restrict__ e,
    const unsigned short* __restrict__ w1s, const unsigned short* __restrict__ w2s,
    const float* __restrict__ ff1b, const float* __restrict__ ff2b,
    const float* __restrict__ ln2g, const float* __restrict__ ln2b,
    float* __restrict__ eout, int l)
{
    __shared__ __align__(16) short Xl[8192];     // 16 KB  X bf16 frag-major: [w][nt][h][q][n][j]
    __shared__ __align__(16) short Act[8192];    // 16 KB  per-wave act
    __shared__ __align__(16) short Wb[2][8192];  // 32 KB  [buf][ W1 4096 | W2 4096 ]
    const int t = threadIdx.x;
    const int w = t >> 6, lane = t & 63;
    const int m_ = lane & 15, qc = lane >> 4;
    const int tok0 = blockIdx.x * 128;

    #pragma unroll
    for (int i = 0; i < 4; ++i) {
        const int g = t + 256 * i;
        const int gw = g >> 8, rem = g & 255;
        const int nt = rem >> 7, h = (rem >> 6) & 1, q = (rem >> 4) & 3, n = rem & 15;
        const int tok = tok0 + gw * 32 + nt * 16 + n;
        const int k = h * 32 + q * 8;
        float4 a = make_float4(0.f, 0.f, 0.f, 0.f), b = a;
        if (tok < N_TOK) {
            a = *(const float4*)(e + tok * 64 + k);
            b = *(const float4*)(e + tok * 64 + k + 4);
        }
        *(uint4*)&Xl[g * 8] = make_uint4(pack2bf(a.x, a.y), pack2bf(a.z, a.w),
                                         pack2bf(b.x, b.y), pack2bf(b.z, b.w));
    }

    const uint4* gw1 = (const uint4*)(w1s + l * 131072);
    const uint4* gw2 = (const uint4*)(w2s + l * 131072);
    uint4 p0 = gw1[t], p1 = gw1[t + 256], p2 = gw2[t], p3 = gw2[t + 256];
    *(uint4*)&Wb[0][t * 8] = p0;               *(uint4*)&Wb[0][(t + 256) * 8] = p1;
    *(uint4*)&Wb[0][4096 + t * 8] = p2;        *(uint4*)&Wb[0][4096 + (t + 256) * 8] = p3;

    f32x4 acc[4][2] = {};

    for (int c = 0; c < 32; ++c) {
        __syncthreads();
        const int buf = c & 1;
        if (c < 31) {
            p0 = gw1[(c + 1) * 512 + t];       p1 = gw1[(c + 1) * 512 + t + 256];
            p2 = gw2[(c + 1) * 512 + t];       p3 = gw2[(c + 1) * 512 + t + 256];
        }
        bf16x8 xb[2][2];
        #pragma unroll
        for (int nt = 0; nt < 2; ++nt)
            #pragma unroll
            for (int h = 0; h < 2; ++h)
                xb[nt][h] = *(const bf16x8*)&Xl[w * 2048 + (nt * 2 + h) * 512 + lane * 8];

        #pragma unroll
        for (int ft = 0; ft < 4; ++ft) {
            const bf16x8 wa0 = *(const bf16x8*)&Wb[buf][(ft * 2 + 0) * 512 + lane * 8];
            const bf16x8 wa1 = *(const bf16x8*)&Wb[buf][(ft * 2 + 1) * 512 + lane * 8];
            const float4 bv = *(const float4*)(ff1b + l * 2048 + c * 64 + ft * 16 + qc * 4);
            f32x4 c0; c0[0] = bv.x; c0[1] = bv.y; c0[2] = bv.z; c0[3] = bv.w;
            f32x4 c1 = c0;
            c0 = MFMA_B16(wa0, xb[0][0], c0); c0 = MFMA_B16(wa1, xb[0][1], c0);
            c1 = MFMA_B16(wa0, xb[1][0], c1); c1 = MFMA_B16(wa1, xb[1][1], c1);
            const int ha = ft >> 1, qa = (ft & 1) * 2 + (qc >> 1), jo = (qc & 1) * 4;
            const int boff = w * 2048 + ha * 512 + qa * 128 + m_ * 8 + jo;
            *(uint2*)&Act[boff] =
                make_uint2(pack2bf(fmaxf(c0[0], 0.f), fmaxf(c0[1], 0.f)),
                           pack2bf(fmaxf(c0[2], 0.f), fmaxf(c0[3], 0.f)));
            *(uint2*)&Act[boff + 1024] =
                make_uint2(pack2bf(fmaxf(c1[0], 0.f), fmaxf(c1[1], 0.f)),
                           pack2bf(fmaxf(c1[2], 0.f), fmaxf(c1[3], 0.f)));
        }
        bf16x8 ab[2][2];
        #pragma unroll
        for (int nt = 0; nt < 2; ++nt)
            #pragma unroll
            for (int h = 0; h < 2; ++h)
                ab[nt][h] = *(const bf16x8*)&Act[w * 2048 + (nt * 2 + h) * 512 + lane * 8];
        #pragma unroll
        for (int ot = 0; ot < 4; ++ot) {
            const bf16x8 w20 = *(const bf16x8*)&Wb[buf][4096 + (ot * 2 + 0) * 512 + lane * 8];
            const bf16x8 w21 = *(const bf16x8*)&Wb[buf][4096 + (ot * 2 + 1) * 512 + lane * 8];
            acc[ot][0] = MFMA_B16(w20, ab[0][0], acc[ot][0]);
            acc[ot][0] = MFMA_B16(w21, ab[0][1], acc[ot][0]);
            acc[ot][1] = MFMA_B16(w20, ab[1][0], acc[ot][1]);
            acc[ot][1] = MFMA_B16(w21, ab[1][1], acc[ot][1]);
        }
        if (c < 31) {
            const int nb = 1 - buf;
            *(uint4*)&Wb[nb][t * 8] = p0;           *(uint4*)&Wb[nb][(t + 256) * 8] = p1;
            *(uint4*)&Wb[nb][4096 + t * 8] = p2;    *(uint4*)&Wb[nb][4096 + (t + 256) * 8] = p3;
        }
    }

    float4 fb2v[4], gv[4], bv2[4];
    #pragma unroll
    for (int ot = 0; ot < 4; ++ot) {
        const int o = l * 64 + ot * 16 + qc * 4;
        fb2v[ot] = *(const float4*)(ff2b + o);
        gv[ot]   = *(const float4*)(ln2g + o);
        bv2[ot]  = *(const float4*)(ln2b + o);
    }
    #pragma unroll
    for (int nt = 0; nt < 2; ++nt) {
        const int tok = tok0 + w * 32 + nt * 16 + m_;
        const bool valid = tok < N_TOK;
        float v[4][4];
        float s = 0.f;
        #pragma unroll
        for (int ot = 0; ot < 4; ++ot) {
            float4 rs = make_float4(0.f, 0.f, 0.f, 0.f);
            if (valid) rs = *(const float4*)(e + tok * 64 + ot * 16 + qc * 4);
            v[ot][0] = acc[ot][nt][0] + fb2v[ot].x + rs.x;
            v[ot][1] = acc[ot][nt][1] + fb2v[ot].y + rs.y;
            v[ot][2] = acc[ot][nt][2] + fb2v[ot].z + rs.z;
            v[ot][3] = acc[ot][nt][3] + fb2v[ot].w + rs.w;
            s += v[ot][0] + v[ot][1] + v[ot][2] + v[ot][3];
        }
        s += __shfl_xor(s, 16); s += __shfl_xor(s, 32);
        const float mean = s * (1.f / 64.f);
        float vs = 0.f;
        #pragma unroll
        for (int ot = 0; ot < 4; ++ot)
            #pragma unroll
            for (int r = 0; r < 4; ++r) { v[ot][r] -= mean; vs += v[ot][r] * v[ot][r]; }
        vs += __shfl_xor(vs, 16); vs += __shfl_xor(vs, 32);
        const float rr = rsqrtf(vs * (1.f / 64.f) + LN_EPS);
        if (valid) {
            #pragma unroll
            for (int ot = 0; ot < 4; ++ot) {
                float4 o4 = make_float4(v[ot][0] * rr * gv[ot].x + bv2[ot].x,
                                        v[ot][1] * rr * gv[ot].y + bv2[ot].y,
                                        v[ot][2] * rr * gv[ot].z + bv2[ot].z,
                                        v[ot][3] * rr * gv[ot].w + bv2[ot].w);
                *(float4*)(eout + tok * 64 + ot * 16 + qc * 4) = o4;
            }
        }
    }
}

// ===================== Kernel 6: mean-pool + 2-layer regressor =====================
__global__ __launch_bounds__(256) void k_reg(
    const float* __restrict__ e,
    const float* __restrict__ r1w, const float* __restrict__ r1b,
    const float* __restrict__ r2w, const float* __restrict__ r2b,
    float* __restrict__ out)
{
    __shared__ float r1T[64][64];
    __shared__ float pld[4][64];
    const int t = threadIdx.x;
    #pragma unroll
    for (int i = 0; i < 4; ++i) {
        const int j  = (t & 15) + 16 * i;
        const int kq = t >> 4;
        const float4 v = *(const float4*)(r1w + j * 64 + kq * 4);
        r1T[kq * 4 + 0][j] = v.x; r1T[kq * 4 + 1][j] = v.y;
        r1T[kq * 4 + 2][j] = v.z; r1T[kq * 4 + 3][j] = v.w;
    }
    const int w = t >> 6, lane = t & 63;
    const int n = blockIdx.x * 4 + w;
    const float p = 0.25f * (e[(n * 4 + 0) * 64 + lane] + e[(n * 4 + 1) * 64 + lane] +
                             e[(n * 4 + 2) * 64 + lane] + e[(n * 4 + 3) * 64 + lane]);
    pld[w][lane] = p;
    __syncthreads();
    float acc = r1b[lane];
    #pragma unroll 8
    for (int k = 0; k < 64; ++k) acc += pld[w][k] * r1T[k][lane];
    acc = fmaxf(acc, 0.f);
    float partial = acc * r2w[lane];
    partial += __shfl_xor(partial, 1);  partial += __shfl_xor(partial, 2);
    partial += __shfl_xor(partial, 4);  partial += __shfl_xor(partial, 8);
    partial += __shfl_xor(partial, 16); partial += __shfl_xor(partial, 32);
    if (lane == 0) out[n] = partial + r2b[0];
}

// ===================== host launcher =====================
extern "C" void kernel_launch(void* const* d_in, const int* in_sizes, int n_in,
                              void* d_out, int out_size, void* d_ws, size_t ws_size,
                              hipStream_t stream) {
    const float* x    = (const float*)d_in[0];
    const int*   ei   = (const int*)d_in[1];
    const float* mpw  = (const float*)d_in[2];
    const float* W0   = (const float*)d_in[3];
    const float* b0   = (const float*)d_in[4];
    const float* Wl   = (const float*)d_in[5];
    const float* bl   = (const float*)d_in[6];
    const float* W1   = (const float*)d_in[7];
    const float* b1   = (const float*)d_in[8];
    const float* Wo   = (const float*)d_in[9];
    const float* bo   = (const float*)d_in[10];
    const float* tinw = (const float*)d_in[11];
    const float* tinb = (const float*)d_in[12];
    const float* tow  = (const float*)d_in[13];
    const float* tob  = (const float*)d_in[14];
    const float* ln1g = (const float*)d_in[15];
    const float* ln1b = (const float*)d_in[16];
    const float* ff1w = (const float*)d_in[17];
    const float* ff1b = (const float*)d_in[18];
    const float* ff2w = (const float*)d_in[19];
    const float* ff2b = (const float*)d_in[20];
    const float* ln2g = (const float*)d_in[21];
    const float* ln2b = (const float*)d_in[22];
    const float* r1w  = (const float*)d_in[23];
    const float* r1b  = (const float*)d_in[24];
    const float* r2w  = (const float*)d_in[25];
    const float* r2b  = (const float*)d_in[26];

    const size_t CH = (size_t)M_P * N_NODES * 64;
    float* y    = (float*)d_ws;
    float* zz   = y + CH;
    float* aggh = zz + CH;
    float* e    = aggh + CH;
    // y region is dead after k_gather — reuse for shuffled bf16 FFN weights
    unsigned short* w1s = (unsigned short*)y;
    unsigned short* w2s = w1s + 262144;
    // e region is dead until k_emb — host the binning temporaries there
    int* off    = (int*)e;                 // N_ROWS+1
    int* cur    = off + (N_ROWS + 1);      // N_ROWS (histogram, then cursor)
    int* binned = cur + N_ROWS;            // M*E

    hipMemsetAsync(cur, 0, N_ROWS * sizeof(int), stream);
    k_lin_yz<<<dim3(469, 8), 256, 0, stream>>>(x, W0, b0, Wl, bl, W1, b1, y, zz);
    k_hist<<<(M_P * E_EDGES) / 256, 256, 0, stream>>>(ei, cur);
    k_scan<<<1, 1024, 0, stream>>>(cur, off);
    hipMemcpyAsync(cur, off, N_ROWS * sizeof(int), hipMemcpyDeviceToDevice, stream);
    k_fill<<<(M_P * E_EDGES) / 256, 256, 0, stream>>>(ei, cur, binned);
    k_gather<<<N_ROWS / 4, 256, 0, stream>>>(off, binned, y, aggh);
    k_emb<<<N_NODES / 16, 256, 0, stream>>>(aggh, zz, Wo, bo, mpw, e);
    k_wshuf<<<1024, 256, 0, stream>>>(ff1w, ff2w, w1s, w2s);
    for (int l = 0; l < 2; ++l) {
        k_attn<<<N_NODES / 8, 256, 0, stream>>>(e, tinw, tinb, tow, tob, ln1g, ln1b, e, l);
        k_ffn_mfma<<<(N_TOK + 127) / 128, 256, 0, stream>>>(e, w1s, w2s, ff1b, ff2b,
                                                            ln2g, ln2b, e, l);
    }
    k_reg<<<N_NODES / 4, 256, 0, stream>>>(e, r1w, r1b, r2w, r2b, (float*)d_out);
}

// Round 4
// 859.812 us; speedup vs baseline: 1.4149x; 1.4149x over previous
//
#include <hip/hip_runtime.h>
#include <hip/hip_bf16.h>
#include <math.h>

#define N_NODES 30000
#define M_P     4
#define E_EDGES 480000
#define N_TOK   (N_NODES * 4)
#define N_ROWS  (M_P * N_NODES)      // 120000 (m,src) rows
#define LN_EPS  1e-5f

typedef short bf16x8 __attribute__((ext_vector_type(8)));
typedef float f32x4  __attribute__((ext_vector_type(4)));
#define MFMA_B16(a, b, c) __builtin_amdgcn_mfma_f32_16x16x32_bf16(a, b, c, 0, 0, 0)

__device__ inline unsigned short f2bf(float f) {
    union { float f; unsigned u; } v; v.f = f;
    unsigned r = v.u + 0x7fffu + ((v.u >> 16) & 1u);
    return (unsigned short)(r >> 16);
}
__device__ inline unsigned pack2bf(float a, float b) {
    return (unsigned)f2bf(a) | ((unsigned)f2bf(b) << 16);
}
__device__ inline float bf2f(short s) {
    union { unsigned u; float f; } v; v.u = ((unsigned)(unsigned short)s) << 16;
    return v.f;
}

// ===================== Kernel 1: y = x@Wl^T ; z = x@(W0+W1)^T + (b0+b1+bl) =====================
__global__ __launch_bounds__(256, 2) void k_lin_yz(
    const float* __restrict__ x,
    const float* __restrict__ W0, const float* __restrict__ b0,
    const float* __restrict__ Wl, const float* __restrict__ bl,
    const float* __restrict__ W1, const float* __restrict__ b1,
    float* __restrict__ y, float* __restrict__ z)
{
    __shared__ float xT[128][68];   // [k][node]
    __shared__ float wT[128][68];   // [k][h]
    const int t     = threadIdx.x;
    const int m     = blockIdx.y >> 1;
    const int which = blockIdx.y & 1;
    const int node0 = blockIdx.x * 64;

    #pragma unroll
    for (int i = 0; i < 8; ++i) {
        const int node = (t & 31) + 32 * (i & 1);
        const int kq   = (t >> 5) + 8 * (i >> 1);
        float4 v = make_float4(0.f, 0.f, 0.f, 0.f);
        const int n = node0 + node;
        if (n < N_NODES) v = *(const float4*)(x + n * 128 + kq * 4);
        xT[kq * 4 + 0][node] = v.x; xT[kq * 4 + 1][node] = v.y;
        xT[kq * 4 + 2][node] = v.z; xT[kq * 4 + 3][node] = v.w;
    }
    #pragma unroll
    for (int i = 0; i < 8; ++i) {
        const int h  = (t & 31) + 32 * (i & 1);
        const int kq = (t >> 5) + 8 * (i >> 1);
        float4 v;
        if (which) {
            v = *(const float4*)(W0 + (m * 64 + h) * 128 + kq * 4);
            const float4 v2 = *(const float4*)(W1 + (m * 64 + h) * 128 + kq * 4);
            v.x += v2.x; v.y += v2.y; v.z += v2.z; v.w += v2.w;
        } else {
            v = *(const float4*)(Wl + (m * 64 + h) * 128 + kq * 4);
        }
        wT[kq * 4 + 0][h] = v.x; wT[kq * 4 + 1][h] = v.y;
        wT[kq * 4 + 2][h] = v.z; wT[kq * 4 + 3][h] = v.w;
    }
    __syncthreads();

    const int tx = t & 15, ty = t >> 4;
    const int hb = tx * 4, nb = ty * 4;
    float acc[4][4] = {};
    #pragma unroll 8
    for (int k = 0; k < 128; ++k) {
        const float4 a = *(const float4*)&xT[k][nb];
        const float4 b = *(const float4*)&wT[k][hb];
        acc[0][0] += a.x * b.x; acc[0][1] += a.x * b.y; acc[0][2] += a.x * b.z; acc[0][3] += a.x * b.w;
        acc[1][0] += a.y * b.x; acc[1][1] += a.y * b.y; acc[1][2] += a.y * b.z; acc[1][3] += a.y * b.w;
        acc[2][0] += a.z * b.x; acc[2][1] += a.z * b.y; acc[2][2] += a.z * b.z; acc[2][3] += a.z * b.w;
        acc[3][0] += a.w * b.x; acc[3][1] += a.w * b.y; acc[3][2] += a.w * b.z; acc[3][3] += a.w * b.w;
    }
    float bias[4] = {0.f, 0.f, 0.f, 0.f};
    if (which) {
        #pragma unroll
        for (int j = 0; j < 4; ++j)
            bias[j] = b0[m * 64 + hb + j] + b1[m * 64 + hb + j] + bl[m * 64 + hb + j];
    }
    float* outp = which ? z : y;
    #pragma unroll
    for (int i = 0; i < 4; ++i) {
        const int n = node0 + nb + i;
        if (n < N_NODES) {
            float4 v = make_float4(acc[i][0] + bias[0], acc[i][1] + bias[1],
                                   acc[i][2] + bias[2], acc[i][3] + bias[3]);
            *(float4*)(outp + (m * N_NODES + n) * 64 + hb) = v;
        }
    }
}

// ===================== Scatter replacement: bin-and-gather (no fp32 atomics) =====================
__global__ __launch_bounds__(256) void k_hist(
    const int* __restrict__ ei, int* __restrict__ cnt)
{
    const int g = blockIdx.x * 256 + threadIdx.x;       // < M*E
    const int m = g / E_EDGES;
    const int e = g - m * E_EDGES;
    const int src = ei[(m * 2) * E_EDGES + e];
    atomicAdd(&cnt[m * N_NODES + src], 1);
}

// Scan phase A: per-block exclusive scan of 1024 counts; off[i] = local excl; bsum[b] = block sum
__global__ __launch_bounds__(1024) void k_scan1(
    const int* __restrict__ cnt, int* __restrict__ off, int* __restrict__ bsum)
{
    __shared__ int wsum[16];
    const int t = threadIdx.x, lane = t & 63, w = t >> 6;
    const int i = blockIdx.x * 1024 + t;
    const int v = (i < N_ROWS) ? cnt[i] : 0;
    int s = v;
    #pragma unroll
    for (int d = 1; d < 64; d <<= 1) {
        const int u = __shfl_up(s, d);
        if (lane >= d) s += u;
    }
    if (lane == 63) wsum[w] = s;
    __syncthreads();
    if (w == 0 && lane < 16) {
        int ws = wsum[lane];
        #pragma unroll
        for (int d = 1; d < 16; d <<= 1) {
            const int u = __shfl_up(ws, d);
            if (lane >= d) ws += u;
        }
        wsum[lane] = ws;
    }
    __syncthreads();
    const int wprev = (w == 0) ? 0 : wsum[w - 1];
    if (i < N_ROWS) off[i] = wprev + s - v;
    if (t == 0) bsum[blockIdx.x] = wsum[15];
}

// Scan phase B: single small block scans 118 block sums → boff (exclusive)
__global__ __launch_bounds__(128) void k_scan2(
    const int* __restrict__ bsum, int* __restrict__ boff, int nblk)
{
    __shared__ int tmp[2];
    const int t = threadIdx.x, lane = t & 63, w = t >> 6;
    const int v = (t < nblk) ? bsum[t] : 0;
    int s = v;
    #pragma unroll
    for (int d = 1; d < 64; d <<= 1) {
        const int u = __shfl_up(s, d);
        if (lane >= d) s += u;
    }
    if (lane == 63) tmp[w] = s;
    __syncthreads();
    const int add = (w == 1) ? tmp[0] : 0;
    if (t < nblk) boff[t] = add + s - v;
}

// Scan phase C: off[i] += boff[b]; cur[i] = off[i] (absorbs the old memcpy)
__global__ __launch_bounds__(1024) void k_scan3(
    int* __restrict__ off, int* __restrict__ cur, const int* __restrict__ boff)
{
    const int i = blockIdx.x * 1024 + threadIdx.x;
    if (i < N_ROWS) {
        const int o = off[i] + boff[blockIdx.x];
        off[i] = o;
        cur[i] = o;
    }
    if (i == 0) off[N_ROWS] = M_P * E_EDGES;
}

// Phase 3: fill bins — binned[pos] = global y-row index of dst
__global__ __launch_bounds__(256) void k_fill(
    const int* __restrict__ ei, int* __restrict__ cur, int* __restrict__ binned)
{
    const int g = blockIdx.x * 256 + threadIdx.x;       // < M*E
    const int m = g / E_EDGES;
    const int e = g - m * E_EDGES;
    const int src = ei[(m * 2) * E_EDGES + e];
    const int dst = ei[(m * 2 + 1) * E_EDGES + e];
    const int pos = atomicAdd(&cur[m * N_NODES + src], 1);
    binned[pos] = m * N_NODES + dst;
}

// Phase 4: gather-reduce — one wave per (m,src) row; lane = feature
__global__ __launch_bounds__(256) void k_gather(
    const int* __restrict__ off, const int* __restrict__ binned,
    const float* __restrict__ y, float* __restrict__ aggh)
{
    const int w = threadIdx.x >> 6, lane = threadIdx.x & 63;
    const int row = blockIdx.x * 4 + w;                 // < N_ROWS
    const int beg = off[row], end = off[row + 1];
    float acc = 0.f;
    for (int i = beg; i < end; i += 64) {
        int idx = 0;
        if (i + lane < end) idx = binned[i + lane];     // coalesced, 1 load / 64 edges
        const int cn = min(64, end - i);
        for (int j = 0; j < cn; ++j) {
            const int r = __shfl(idx, j);               // broadcast row index
            acc += y[r * 64 + lane];                    // 256 B contiguous, L3-resident
        }
    }
    aggh[row * 64 + lane] = acc;
}

// ===================== Kernel 3: e[n][m][:] = (relu(aggh+z) @ Wo^T + bo) * mpw[m] =====================
__global__ __launch_bounds__(256) void k_emb(
    const float* __restrict__ aggh, const float* __restrict__ z,
    const float* __restrict__ Wo, const float* __restrict__ bo,
    const float* __restrict__ mpw, float* __restrict__ e)
{
    __shared__ float hT[64][20];
    __shared__ float WoT[64][64];
    const int t = threadIdx.x;
    const int node0 = blockIdx.x * 16;

    for (int m = 0; m < 4; ++m) {
        #pragma unroll
        for (int i = 0; i < 4; ++i) {
            const int o  = (t & 15) + 16 * i;
            const int kq = t >> 4;
            const float4 v = *(const float4*)(Wo + (m * 64 + o) * 64 + kq * 4);
            WoT[kq * 4 + 0][o] = v.x; WoT[kq * 4 + 1][o] = v.y;
            WoT[kq * 4 + 2][o] = v.z; WoT[kq * 4 + 3][o] = v.w;
        }
        {
            const int node = t & 15, kq = t >> 4;
            const int n = node0 + node;
            const float4 a = *(const float4*)(aggh + (m * N_NODES + n) * 64 + kq * 4);
            const float4 b = *(const float4*)(z + (m * N_NODES + n) * 64 + kq * 4);
            hT[kq * 4 + 0][node] = fmaxf(a.x + b.x, 0.f);
            hT[kq * 4 + 1][node] = fmaxf(a.y + b.y, 0.f);
            hT[kq * 4 + 2][node] = fmaxf(a.z + b.z, 0.f);
            hT[kq * 4 + 3][node] = fmaxf(a.w + b.w, 0.f);
        }
        __syncthreads();
        const int o = t & 63, nl4 = (t >> 6) * 4;
        float acc[4] = {};
        #pragma unroll 8
        for (int k = 0; k < 64; ++k) {
            const float bw = WoT[k][o];
            const float4 a = *(const float4*)&hT[k][nl4];
            acc[0] += a.x * bw; acc[1] += a.y * bw; acc[2] += a.z * bw; acc[3] += a.w * bw;
        }
        const float bb = bo[m * 64 + o];
        const float w  = mpw[m];
        #pragma unroll
        for (int i = 0; i < 4; ++i)
            e[((node0 + nl4 + i) * 4 + m) * 64 + o] = (acc[i] + bb) * w;
        __syncthreads();
    }
}

// ===================== Kernel 4: attention via bf16 MFMA (qkv + softmax + proj + residual + LN1) ==========
// 128 tok/block, 4 independent waves x 32 tok (8 nodes). NO barriers: each wave touches only its own
// LDS slots; O-fragments overwrite the wave's dead X slot (same-wave RAW, like FFN's Act trick).
__global__ __launch_bounds__(256, 2) void k_attn_mfma(
    const float* __restrict__ e,
    const unsigned short* __restrict__ wqkv_s, const float* __restrict__ tinb,
    const unsigned short* __restrict__ tow_s, const float* __restrict__ tob,
    const float* __restrict__ ln1g, const float* __restrict__ ln1b,
    float* __restrict__ eout, int l)
{
    __shared__ __align__(16) short Xl[8192];      // 16 KB [w][2048]: X B-frags, then O B-frags
    __shared__ __align__(16) short QKV[25600];    // 50 KB [w][tok(32)][200]: q|k|v bf16, row=200 for align
    const int t = threadIdx.x;
    const int w = t >> 6, lane = t & 63;
    const int m_ = lane & 15, qc = lane >> 4;
    const int tok0 = blockIdx.x * 128;
    short* Xw = &Xl[w * 2048];
    short* Qw = &QKV[w * 6400];

    // ---- stage own wave's 32 tokens, bf16 frag-major ----
    #pragma unroll
    for (int i = 0; i < 4; ++i) {
        const int rem = lane + 64 * i;              // [0,256) groups of 8 elems
        const int nt = rem >> 7, h = (rem >> 6) & 1, q = (rem >> 4) & 3, n = rem & 15;
        const int tok = tok0 + w * 32 + nt * 16 + n;
        const int k0 = h * 32 + q * 8;
        float4 a = make_float4(0.f, 0.f, 0.f, 0.f), b = a;
        if (tok < N_TOK) {
            a = *(const float4*)(e + tok * 64 + k0);
            b = *(const float4*)(e + tok * 64 + k0 + 4);
        }
        *(uint4*)&Xw[rem * 8] = make_uint4(pack2bf(a.x, a.y), pack2bf(a.z, a.w),
                                           pack2bf(b.x, b.y), pack2bf(b.z, b.w));
    }

    // ---- GEMM1: qkv[f][tok] = tinw @ X^T + tinb  (A-frags direct from global, L2-resident) ----
    bf16x8 xb[2][2];
    #pragma unroll
    for (int nt = 0; nt < 2; ++nt)
        #pragma unroll
        for (int h = 0; h < 2; ++h)
            xb[nt][h] = *(const bf16x8*)&Xw[(nt * 2 + h) * 512 + lane * 8];

    const unsigned short* Wq = wqkv_s + l * 12288;
    f32x4 acc[12][2];
    #pragma unroll
    for (int ft = 0; ft < 12; ++ft) {
        const bf16x8 wa0 = *(const bf16x8*)(Wq + (ft * 2 + 0) * 512 + lane * 8);
        const bf16x8 wa1 = *(const bf16x8*)(Wq + (ft * 2 + 1) * 512 + lane * 8);
        const float4 bv = *(const float4*)(tinb + l * 192 + ft * 16 + qc * 4);
        f32x4 c0; c0[0] = bv.x; c0[1] = bv.y; c0[2] = bv.z; c0[3] = bv.w;
        f32x4 c1 = c0;
        c0 = MFMA_B16(wa0, xb[0][0], c0); c0 = MFMA_B16(wa1, xb[0][1], c0);
        c1 = MFMA_B16(wa0, xb[1][0], c1); c1 = MFMA_B16(wa1, xb[1][1], c1);
        acc[ft][0] = c0; acc[ft][1] = c1;
    }
    // write qkv to own wave's LDS slot: lane holds qkv[f=ft*16+qc*4+r][tok=nt*16+m_]
    #pragma unroll
    for (int ft = 0; ft < 12; ++ft)
        #pragma unroll
        for (int nt = 0; nt < 2; ++nt) {
            const int addr = (nt * 16 + m_) * 200 + ft * 16 + qc * 4;
            *(uint2*)&Qw[addr] = make_uint2(pack2bf(acc[ft][nt][0], acc[ft][nt][1]),
                                            pack2bf(acc[ft][nt][2], acc[ft][nt][3]));
        }

    // ---- attention: one lane per (node, head); node = lane>>3 in [0,8), head = lane&7 ----
    {
        const int node = lane >> 3, head = lane & 7;
        float kk[4][8], vv[4][8];
        #pragma unroll
        for (int j2 = 0; j2 < 4; ++j2) {
            const bf16x8 kr = *(const bf16x8*)&Qw[(node * 4 + j2) * 200 + 64 + head * 8];
            const bf16x8 vr = *(const bf16x8*)&Qw[(node * 4 + j2) * 200 + 128 + head * 8];
            #pragma unroll
            for (int d = 0; d < 8; ++d) { kk[j2][d] = bf2f(kr[d]); vv[j2][d] = bf2f(vr[d]); }
        }
        const float scale = 0.35355339059327373f;   // 1/sqrt(8)
        const int nt = node >> 2, hq = head >> 2, qq = head & 3;
        #pragma unroll
        for (int i = 0; i < 4; ++i) {
            const bf16x8 qr = *(const bf16x8*)&Qw[(node * 4 + i) * 200 + head * 8];
            float q[8];
            #pragma unroll
            for (int d = 0; d < 8; ++d) q[d] = bf2f(qr[d]);
            float s[4];
            #pragma unroll
            for (int j2 = 0; j2 < 4; ++j2) {
                float a2 = 0.f;
                #pragma unroll
                for (int d = 0; d < 8; ++d) a2 += q[d] * kk[j2][d];
                s[j2] = a2 * scale;
            }
            const float mx = fmaxf(fmaxf(s[0], s[1]), fmaxf(s[2], s[3]));
            float p[4], sum = 0.f;
            #pragma unroll
            for (int j2 = 0; j2 < 4; ++j2) { p[j2] = __expf(s[j2] - mx); sum += p[j2]; }
            const float inv = 1.f / sum;
            float o[8];
            #pragma unroll
            for (int d = 0; d < 8; ++d)
                o[d] = (p[0] * vv[0][d] + p[1] * vv[1][d] + p[2] * vv[2][d] + p[3] * vv[3][d]) * inv;
            // store O as B-frag for out-proj GEMM: k = head*8+d, tok n = (node&3)*4+i
            const int n = (node & 3) * 4 + i;
            *(uint4*)&Xw[(nt * 2 + hq) * 512 + qq * 128 + n * 8] =
                make_uint4(pack2bf(o[0], o[1]), pack2bf(o[2], o[3]),
                           pack2bf(o[4], o[5]), pack2bf(o[6], o[7]));
        }
    }

    // ---- GEMM2: out[o][tok] = tow @ O^T ----
    bf16x8 ob[2][2];
    #pragma unroll
    for (int nt = 0; nt < 2; ++nt)
        #pragma unroll
        for (int h = 0; h < 2; ++h)
            ob[nt][h] = *(const bf16x8*)&Xw[(nt * 2 + h) * 512 + lane * 8];
    const unsigned short* Tw = tow_s + l * 4096;
    f32x4 acc2[4][2] = {};
    #pragma unroll
    for (int ot = 0; ot < 4; ++ot) {
        const bf16x8 t0 = *(const bf16x8*)(Tw + (ot * 2 + 0) * 512 + lane * 8);
        const bf16x8 t1 = *(const bf16x8*)(Tw + (ot * 2 + 1) * 512 + lane * 8);
        acc2[ot][0] = MFMA_B16(t0, ob[0][0], acc2[ot][0]);
        acc2[ot][0] = MFMA_B16(t1, ob[0][1], acc2[ot][0]);
        acc2[ot][1] = MFMA_B16(t0, ob[1][0], acc2[ot][1]);
        acc2[ot][1] = MFMA_B16(t1, ob[1][1], acc2[ot][1]);
    }

    // ---- epilogue: + tob + residual(fp32), LN1, store ----
    float4 tbv[4], gv[4], bv2[4];
    #pragma unroll
    for (int ot = 0; ot < 4; ++ot) {
        const int o = l * 64 + ot * 16 + qc * 4;
        tbv[ot] = *(const float4*)(tob + o);
        gv[ot]  = *(const float4*)(ln1g + o);
        bv2[ot] = *(const float4*)(ln1b + o);
    }
    #pragma unroll
    for (int nt = 0; nt < 2; ++nt) {
        const int tok = tok0 + w * 32 + nt * 16 + m_;
        const bool valid = tok < N_TOK;
        float v[4][4];
        float s = 0.f;
        #pragma unroll
        for (int ot = 0; ot < 4; ++ot) {
            float4 rs = make_float4(0.f, 0.f, 0.f, 0.f);
            if (valid) rs = *(const float4*)(e + tok * 64 + ot * 16 + qc * 4);
            v[ot][0] = acc2[ot][nt][0] + tbv[ot].x + rs.x;
            v[ot][1] = acc2[ot][nt][1] + tbv[ot].y + rs.y;
            v[ot][2] = acc2[ot][nt][2] + tbv[ot].z + rs.z;
            v[ot][3] = acc2[ot][nt][3] + tbv[ot].w + rs.w;
            s += v[ot][0] + v[ot][1] + v[ot][2] + v[ot][3];
        }
        s += __shfl_xor(s, 16); s += __shfl_xor(s, 32);
        const float mean = s * (1.f / 64.f);
        float vs = 0.f;
        #pragma unroll
        for (int ot = 0; ot < 4; ++ot)
            #pragma unroll
            for (int r = 0; r < 4; ++r) { v[ot][r] -= mean; vs += v[ot][r] * v[ot][r]; }
        vs += __shfl_xor(vs, 16); vs += __shfl_xor(vs, 32);
        const float rr = rsqrtf(vs * (1.f / 64.f) + LN_EPS);
        if (valid) {
            #pragma unroll
            for (int ot = 0; ot < 4; ++ot) {
                float4 o4 = make_float4(v[ot][0] * rr * gv[ot].x + bv2[ot].x,
                                        v[ot][1] * rr * gv[ot].y + bv2[ot].y,
                                        v[ot][2] * rr * gv[ot].z + bv2[ot].z,
                                        v[ot][3] * rr * gv[ot].w + bv2[ot].w);
                *(float4*)(eout + tok * 64 + ot * 16 + qc * 4) = o4;
            }
        }
    }
}

// ===================== Kernel 4.5: pre-shuffle weights to MFMA-fragment-major bf16 =====================
__global__ __launch_bounds__(256) void k_wshuf(
    const float* __restrict__ ff1w, const float* __restrict__ ff2w,
    const float* __restrict__ tinw, const float* __restrict__ tow,
    unsigned short* __restrict__ w1s, unsigned short* __restrict__ w2s,
    unsigned short* __restrict__ wqkv_s, unsigned short* __restrict__ tow_s)
{
    const int g = blockIdx.x * 256 + threadIdx.x;   // [0, 262144)
    {
        const int l = g >> 17, r2 = g & 131071;
        const int f = r2 >> 6, k = r2 & 63;
        const int c = f >> 6, fc = f & 63, ft = fc >> 4, m = fc & 15;
        const int h = k >> 5, q = (k >> 3) & 3, j = k & 7;
        w1s[l * 131072 + c * 4096 + (ft * 2 + h) * 512 + (q * 16 + m) * 8 + j] = f2bf(ff1w[g]);
    }
    {
        const int l = g >> 17, r2 = g & 131071;
        const int o = r2 >> 11, f = r2 & 2047;
        const int c = f >> 6, fc = f & 63, h = fc >> 5, q = (fc >> 3) & 3, j = fc & 7;
        const int ot = o >> 4, m = o & 15;
        w2s[l * 131072 + c * 4096 + (ot * 2 + h) * 512 + (q * 16 + m) * 8 + j] = f2bf(ff2w[g]);
    }
    if (g < 2 * 192 * 64) {        // qkv in_proj: A-frag, M=f(192), K=64
        const int l = g / 12288, r2 = g - l * 12288;
        const int f = r2 >> 6, k = r2 & 63;
        const int ft = f >> 4, m = f & 15;
        const int h = k >> 5, q = (k >> 3) & 3, j = k & 7;
        wqkv_s[l * 12288 + (ft * 2 + h) * 512 + (q * 16 + m) * 8 + j] = f2bf(tinw[g]);
    }
    if (g < 2 * 64 * 64) {         // out_proj: A-frag, M=o(64), K=64
        const int l = g >> 12, r2 = g & 4095;
        const int o = r2 >> 6, k = r2 & 63;
        const int ot = o >> 4, m = o & 15;
        const int h = k >> 5, q = (k >> 3) & 3, j = k & 7;
        tow_s[l * 4096 + (ot * 2 + h) * 512 + (q * 16 + m) * 8 + j] = f2bf(tow[g]);
    }
}

// ===================== Kernel 5: FFN via bf16 MFMA (fused relu-MLP + residual + LN2) =====================
__global__ __launch_bounds__(256, 2) void k_ffn_mfma(
    const float* __restrict__ e,
    const unsigned short* __restrict__ w1s, const unsigned short* __restrict__ w2s,
    const float* __restrict__ ff1b, const float* __restrict__ ff2b,
    const float* __restrict__ ln2g, const float* __restrict__ ln2b,
    float* __restrict__ eout, int l)
{
    __shared__ __align__(16) short Xl[8192];     // 16 KB
    __shared__ __align__(16) short Act[8192];    // 16 KB
    __shared__ __align__(16) short Wb[2][8192];  // 32 KB
    const int t = threadIdx.x;
    const int w = t >> 6, lane = t & 63;
    const int m_ = lane & 15, qc = lane >> 4;
    const int tok0 = blockIdx.x * 128;

    #pragma unroll
    for (int i = 0; i < 4; ++i) {
        const int g = t + 256 * i;
        const int gw = g >> 8, rem = g & 255;
        const int nt = rem >> 7, h = (rem >> 6) & 1, q = (rem >> 4) & 3, n = rem & 15;
        const int tok = tok0 + gw * 32 + nt * 16 + n;
        const int k = h * 32 + q * 8;
        float4 a = make_float4(0.f, 0.f, 0.f, 0.f), b = a;
        if (tok < N_TOK) {
            a = *(const float4*)(e + tok * 64 + k);
            b = *(const float4*)(e + tok * 64 + k + 4);
        }
        *(uint4*)&Xl[g * 8] = make_uint4(pack2bf(a.x, a.y), pack2bf(a.z, a.w),
                                         pack2bf(b.x, b.y), pack2bf(b.z, b.w));
    }

    const uint4* gw1 = (const uint4*)(w1s + l * 131072);
    const uint4* gw2 = (const uint4*)(w2s + l * 131072);
    uint4 p0 = gw1[t], p1 = gw1[t + 256], p2 = gw2[t], p3 = gw2[t + 256];
    *(uint4*)&Wb[0][t * 8] = p0;               *(uint4*)&Wb[0][(t + 256) * 8] = p1;
    *(uint4*)&Wb[0][4096 + t * 8] = p2;        *(uint4*)&Wb[0][4096 + (t + 256) * 8] = p3;

    f32x4 acc[4][2] = {};

    for (int c = 0; c < 32; ++c) {
        __syncthreads();
        const int buf = c & 1;
        if (c < 31) {
            p0 = gw1[(c + 1) * 512 + t];       p1 = gw1[(c + 1) * 512 + t + 256];
            p2 = gw2[(c + 1) * 512 + t];       p3 = gw2[(c + 1) * 512 + t + 256];
        }
        bf16x8 xb[2][2];
        #pragma unroll
        for (int nt = 0; nt < 2; ++nt)
            #pragma unroll
            for (int h = 0; h < 2; ++h)
                xb[nt][h] = *(const bf16x8*)&Xl[w * 2048 + (nt * 2 + h) * 512 + lane * 8];

        #pragma unroll
        for (int ft = 0; ft < 4; ++ft) {
            const bf16x8 wa0 = *(const bf16x8*)&Wb[buf][(ft * 2 + 0) * 512 + lane * 8];
            const bf16x8 wa1 = *(const bf16x8*)&Wb[buf][(ft * 2 + 1) * 512 + lane * 8];
            const float4 bv = *(const float4*)(ff1b + l * 2048 + c * 64 + ft * 16 + qc * 4);
            f32x4 c0; c0[0] = bv.x; c0[1] = bv.y; c0[2] = bv.z; c0[3] = bv.w;
            f32x4 c1 = c0;
            c0 = MFMA_B16(wa0, xb[0][0], c0); c0 = MFMA_B16(wa1, xb[0][1], c0);
            c1 = MFMA_B16(wa0, xb[1][0], c1); c1 = MFMA_B16(wa1, xb[1][1], c1);
            const int ha = ft >> 1, qa = (ft & 1) * 2 + (qc >> 1), jo = (qc & 1) * 4;
            const int boff = w * 2048 + ha * 512 + qa * 128 + m_ * 8 + jo;
            *(uint2*)&Act[boff] =
                make_uint2(pack2bf(fmaxf(c0[0], 0.f), fmaxf(c0[1], 0.f)),
                           pack2bf(fmaxf(c0[2], 0.f), fmaxf(c0[3], 0.f)));
            *(uint2*)&Act[boff + 1024] =
                make_uint2(pack2bf(fmaxf(c1[0], 0.f), fmaxf(c1[1], 0.f)),
                           pack2bf(fmaxf(c1[2], 0.f), fmaxf(c1[3], 0.f)));
        }
        bf16x8 ab[2][2];
        #pragma unroll
        for (int nt = 0; nt < 2; ++nt)
            #pragma unroll
            for (int h = 0; h < 2; ++h)
                ab[nt][h] = *(const bf16x8*)&Act[w * 2048 + (nt * 2 + h) * 512 + lane * 8];
        #pragma unroll
        for (int ot = 0; ot < 4; ++ot) {
            const bf16x8 w20 = *(const bf16x8*)&Wb[buf][4096 + (ot * 2 + 0) * 512 + lane * 8];
            const bf16x8 w21 = *(const bf16x8*)&Wb[buf][4096 + (ot * 2 + 1) * 512 + lane * 8];
            acc[ot][0] = MFMA_B16(w20, ab[0][0], acc[ot][0]);
            acc[ot][0] = MFMA_B16(w21, ab[0][1], acc[ot][0]);
            acc[ot][1] = MFMA_B16(w20, ab[1][0], acc[ot][1]);
            acc[ot][1] = MFMA_B16(w21, ab[1][1], acc[ot][1]);
        }
        if (c < 31) {
            const int nb = 1 - buf;
            *(uint4*)&Wb[nb][t * 8] = p0;           *(uint4*)&Wb[nb][(t + 256) * 8] = p1;
            *(uint4*)&Wb[nb][4096 + t * 8] = p2;    *(uint4*)&Wb[nb][4096 + (t + 256) * 8] = p3;
        }
    }

    float4 fb2v[4], gv[4], bv2[4];
    #pragma unroll
    for (int ot = 0; ot < 4; ++ot) {
        const int o = l * 64 + ot * 16 + qc * 4;
        fb2v[ot] = *(const float4*)(ff2b + o);
        gv[ot]   = *(const float4*)(ln2g + o);
        bv2[ot]  = *(const float4*)(ln2b + o);
    }
    #pragma unroll
    for (int nt = 0; nt < 2; ++nt) {
        const int tok = tok0 + w * 32 + nt * 16 + m_;
        const bool valid = tok < N_TOK;
        float v[4][4];
        float s = 0.f;
        #pragma unroll
        for (int ot = 0; ot < 4; ++ot) {
            float4 rs = make_float4(0.f, 0.f, 0.f, 0.f);
            if (valid) rs = *(const float4*)(e + tok * 64 + ot * 16 + qc * 4);
            v[ot][0] = acc[ot][nt][0] + fb2v[ot].x + rs.x;
            v[ot][1] = acc[ot][nt][1] + fb2v[ot].y + rs.y;
            v[ot][2] = acc[ot][nt][2] + fb2v[ot].z + rs.z;
            v[ot][3] = acc[ot][nt][3] + fb2v[ot].w + rs.w;
            s += v[ot][0] + v[ot][1] + v[ot][2] + v[ot][3];
        }
        s += __shfl_xor(s, 16); s += __shfl_xor(s, 32);
        const float mean = s * (1.f / 64.f);
        float vs = 0.f;
        #pragma unroll
        for (int ot = 0; ot < 4; ++ot)
            #pragma unroll
            for (int r = 0; r < 4; ++r) { v[ot][r] -= mean; vs += v[ot][r] * v[ot][r]; }
        vs += __shfl_xor(vs, 16); vs += __shfl_xor(vs, 32);
        const float rr = rsqrtf(vs * (1.f / 64.f) + LN_EPS);
        if (valid) {
            #pragma unroll
            for (int ot = 0; ot < 4; ++ot) {
                float4 o4 = make_float4(v[ot][0] * rr * gv[ot].x + bv2[ot].x,
                                        v[ot][1] * rr * gv[ot].y + bv2[ot].y,
                                        v[ot][2] * rr * gv[ot].z + bv2[ot].z,
                                        v[ot][3] * rr * gv[ot].w + bv2[ot].w);
                *(float4*)(eout + tok * 64 + ot * 16 + qc * 4) = o4;
            }
        }
    }
}

// ===================== Kernel 6: mean-pool + 2-layer regressor =====================
__global__ __launch_bounds__(256) void k_reg(
    const float* __restrict__ e,
    const float* __restrict__ r1w, const float* __restrict__ r1b,
    const float* __restrict__ r2w, const float* __restrict__ r2b,
    float* __restrict__ out)
{
    __shared__ float r1T[64][64];
    __shared__ float pld[4][64];
    const int t = threadIdx.x;
    #pragma unroll
    for (int i = 0; i < 4; ++i) {
        const int j  = (t & 15) + 16 * i;
        const int kq = t >> 4;
        const float4 v = *(const float4*)(r1w + j * 64 + kq * 4);
        r1T[kq * 4 + 0][j] = v.x; r1T[kq * 4 + 1][j] = v.y;
        r1T[kq * 4 + 2][j] = v.z; r1T[kq * 4 + 3][j] = v.w;
    }
    const int w = t >> 6, lane = t & 63;
    const int n = blockIdx.x * 4 + w;
    const float p = 0.25f * (e[(n * 4 + 0) * 64 + lane] + e[(n * 4 + 1) * 64 + lane] +
                             e[(n * 4 + 2) * 64 + lane] + e[(n * 4 + 3) * 64 + lane]);
    pld[w][lane] = p;
    __syncthreads();
    float acc = r1b[lane];
    #pragma unroll 8
    for (int k = 0; k < 64; ++k) acc += pld[w][k] * r1T[k][lane];
    acc = fmaxf(acc, 0.f);
    float partial = acc * r2w[lane];
    partial += __shfl_xor(partial, 1);  partial += __shfl_xor(partial, 2);
    partial += __shfl_xor(partial, 4);  partial += __shfl_xor(partial, 8);
    partial += __shfl_xor(partial, 16); partial += __shfl_xor(partial, 32);
    if (lane == 0) out[n] = partial + r2b[0];
}

// ===================== host launcher =====================
extern "C" void kernel_launch(void* const* d_in, const int* in_sizes, int n_in,
                              void* d_out, int out_size, void* d_ws, size_t ws_size,
                              hipStream_t stream) {
    const float* x    = (const float*)d_in[0];
    const int*   ei   = (const int*)d_in[1];
    const float* mpw  = (const float*)d_in[2];
    const float* W0   = (const float*)d_in[3];
    const float* b0   = (const float*)d_in[4];
    const float* Wl   = (const float*)d_in[5];
    const float* bl   = (const float*)d_in[6];
    const float* W1   = (const float*)d_in[7];
    const float* b1   = (const float*)d_in[8];
    const float* Wo   = (const float*)d_in[9];
    const float* bo   = (const float*)d_in[10];
    const float* tinw = (const float*)d_in[11];
    const float* tinb = (const float*)d_in[12];
    const float* tow  = (const float*)d_in[13];
    const float* tob  = (const float*)d_in[14];
    const float* ln1g = (const float*)d_in[15];
    const float* ln1b = (const float*)d_in[16];
    const float* ff1w = (const float*)d_in[17];
    const float* ff1b = (const float*)d_in[18];
    const float* ff2w = (const float*)d_in[19];
    const float* ff2b = (const float*)d_in[20];
    const float* ln2g = (const float*)d_in[21];
    const float* ln2b = (const float*)d_in[22];
    const float* r1w  = (const float*)d_in[23];
    const float* r1b  = (const float*)d_in[24];
    const float* r2w  = (const float*)d_in[25];
    const float* r2b  = (const float*)d_in[26];

    const size_t CH = (size_t)M_P * N_NODES * 64;
    float* y    = (float*)d_ws;
    float* zz   = y + CH;
    float* aggh = zz + CH;
    float* e    = aggh + CH;
    // y region is dead after k_gather — reuse for shuffled bf16 weights
    unsigned short* w1s    = (unsigned short*)y;
    unsigned short* w2s    = w1s + 262144;
    unsigned short* wqkv_s = w2s + 262144;
    unsigned short* tow_s  = wqkv_s + 24576;
    // e region is dead until k_emb — host the binning temporaries there
    int* off    = (int*)e;                 // N_ROWS+1
    int* cur    = off + (N_ROWS + 1);      // N_ROWS (histogram, then cursor)
    int* binned = cur + N_ROWS;            // M*E
    int* bsum   = binned + M_P * E_EDGES;  // 118 block sums
    int* boff   = bsum + 128;              // 118 block offsets

    const int SCAN_BLKS = (N_ROWS + 1023) / 1024;   // 118

    hipMemsetAsync(cur, 0, N_ROWS * sizeof(int), stream);
    k_lin_yz<<<dim3(469, 8), 256, 0, stream>>>(x, W0, b0, Wl, bl, W1, b1, y, zz);
    k_hist<<<(M_P * E_EDGES) / 256, 256, 0, stream>>>(ei, cur);
    k_scan1<<<SCAN_BLKS, 1024, 0, stream>>>(cur, off, bsum);
    k_scan2<<<1, 128, 0, stream>>>(bsum, boff, SCAN_BLKS);
    k_scan3<<<SCAN_BLKS, 1024, 0, stream>>>(off, cur, boff);
    k_fill<<<(M_P * E_EDGES) / 256, 256, 0, stream>>>(ei, cur, binned);
    k_gather<<<N_ROWS / 4, 256, 0, stream>>>(off, binned, y, aggh);
    k_emb<<<N_NODES / 16, 256, 0, stream>>>(aggh, zz, Wo, bo, mpw, e);
    k_wshuf<<<1024, 256, 0, stream>>>(ff1w, ff2w, tinw, tow, w1s, w2s, wqkv_s, tow_s);
    for (int l = 0; l < 2; ++l) {
        k_attn_mfma<<<(N_TOK + 127) / 128, 256, 0, stream>>>(e, wqkv_s, tinb, tow_s, tob,
                                                             ln1g, ln1b, e, l);
        k_ffn_mfma<<<(N_TOK + 127) / 128, 256, 0, stream>>>(e, w1s, w2s, ff1b, ff2b,
                                                            ln2g, ln2b, e, l);
    }
    k_reg<<<N_NODES / 4, 256, 0, stream>>>(e, r1w, r1b, r2w, r2b, (float*)d_out);
}

// Round 5
// 829.927 us; speedup vs baseline: 1.4658x; 1.0360x over previous
//
#include <hip/hip_runtime.h>
#include <hip/hip_bf16.h>
#include <math.h>

#define N_NODES 30000
#define M_P     4
#define E_EDGES 480000
#define N_TOK   (N_NODES * 4)
#define N_ROWS  (M_P * N_NODES)      // 120000 (m,src) rows
#define LN_EPS  1e-5f

typedef short bf16x8 __attribute__((ext_vector_type(8)));
typedef float f32x4  __attribute__((ext_vector_type(4)));
#define MFMA_B16(a, b, c) __builtin_amdgcn_mfma_f32_16x16x32_bf16(a, b, c, 0, 0, 0)

__device__ inline unsigned short f2bf(float f) {
    union { float f; unsigned u; } v; v.f = f;
    unsigned r = v.u + 0x7fffu + ((v.u >> 16) & 1u);
    return (unsigned short)(r >> 16);
}
// HW packed cvt (v_cvt_pk_bf16_f32, RNE — same rounding as f2bf)
__device__ inline unsigned pack2bf(float a, float b) {
    union { __hip_bfloat162 h; unsigned u; } cv;
    cv.h = __float22bfloat162_rn(make_float2(a, b));
    return cv.u;
}
__device__ inline float bf2f(short s) {
    union { unsigned u; float f; } v; v.u = ((unsigned)(unsigned short)s) << 16;
    return v.f;
}

// ===================== Kernel 1: y = x@Wl^T ; z = x@(W0+W1)^T + (b0+b1+bl) =====================
__global__ __launch_bounds__(256, 2) void k_lin_yz(
    const float* __restrict__ x,
    const float* __restrict__ W0, const float* __restrict__ b0,
    const float* __restrict__ Wl, const float* __restrict__ bl,
    const float* __restrict__ W1, const float* __restrict__ b1,
    float* __restrict__ y, float* __restrict__ z)
{
    __shared__ float xT[128][68];   // [k][node]
    __shared__ float wT[128][68];   // [k][h]
    const int t     = threadIdx.x;
    const int m     = blockIdx.y >> 1;
    const int which = blockIdx.y & 1;
    const int node0 = blockIdx.x * 64;

    #pragma unroll
    for (int i = 0; i < 8; ++i) {
        const int node = (t & 31) + 32 * (i & 1);
        const int kq   = (t >> 5) + 8 * (i >> 1);
        float4 v = make_float4(0.f, 0.f, 0.f, 0.f);
        const int n = node0 + node;
        if (n < N_NODES) v = *(const float4*)(x + n * 128 + kq * 4);
        xT[kq * 4 + 0][node] = v.x; xT[kq * 4 + 1][node] = v.y;
        xT[kq * 4 + 2][node] = v.z; xT[kq * 4 + 3][node] = v.w;
    }
    #pragma unroll
    for (int i = 0; i < 8; ++i) {
        const int h  = (t & 31) + 32 * (i & 1);
        const int kq = (t >> 5) + 8 * (i >> 1);
        float4 v;
        if (which) {
            v = *(const float4*)(W0 + (m * 64 + h) * 128 + kq * 4);
            const float4 v2 = *(const float4*)(W1 + (m * 64 + h) * 128 + kq * 4);
            v.x += v2.x; v.y += v2.y; v.z += v2.z; v.w += v2.w;
        } else {
            v = *(const float4*)(Wl + (m * 64 + h) * 128 + kq * 4);
        }
        wT[kq * 4 + 0][h] = v.x; wT[kq * 4 + 1][h] = v.y;
        wT[kq * 4 + 2][h] = v.z; wT[kq * 4 + 3][h] = v.w;
    }
    __syncthreads();

    const int tx = t & 15, ty = t >> 4;
    const int hb = tx * 4, nb = ty * 4;
    float acc[4][4] = {};
    #pragma unroll 8
    for (int k = 0; k < 128; ++k) {
        const float4 a = *(const float4*)&xT[k][nb];
        const float4 b = *(const float4*)&wT[k][hb];
        acc[0][0] += a.x * b.x; acc[0][1] += a.x * b.y; acc[0][2] += a.x * b.z; acc[0][3] += a.x * b.w;
        acc[1][0] += a.y * b.x; acc[1][1] += a.y * b.y; acc[1][2] += a.y * b.z; acc[1][3] += a.y * b.w;
        acc[2][0] += a.z * b.x; acc[2][1] += a.z * b.y; acc[2][2] += a.z * b.z; acc[2][3] += a.z * b.w;
        acc[3][0] += a.w * b.x; acc[3][1] += a.w * b.y; acc[3][2] += a.w * b.z; acc[3][3] += a.w * b.w;
    }
    float bias[4] = {0.f, 0.f, 0.f, 0.f};
    if (which) {
        #pragma unroll
        for (int j = 0; j < 4; ++j)
            bias[j] = b0[m * 64 + hb + j] + b1[m * 64 + hb + j] + bl[m * 64 + hb + j];
    }
    float* outp = which ? z : y;
    #pragma unroll
    for (int i = 0; i < 4; ++i) {
        const int n = node0 + nb + i;
        if (n < N_NODES) {
            float4 v = make_float4(acc[i][0] + bias[0], acc[i][1] + bias[1],
                                   acc[i][2] + bias[2], acc[i][3] + bias[3]);
            *(float4*)(outp + (m * N_NODES + n) * 64 + hb) = v;
        }
    }
}

// ===================== Scatter replacement: bin-and-gather (no fp32 atomics) =====================
// Phase 1: histogram, 4 independent edges/thread for atomic-latency ILP
__global__ __launch_bounds__(256) void k_hist(
    const int* __restrict__ ei, int* __restrict__ cnt)
{
    const int base = blockIdx.x * 1024 + threadIdx.x;
    #pragma unroll
    for (int i = 0; i < 4; ++i) {
        const int g = base + i * 256;                   // coalesced per i
        const int m = g / E_EDGES;
        const int e = g - m * E_EDGES;
        atomicAdd(&cnt[m * N_NODES + ei[(m * 2) * E_EDGES + e]], 1);
    }
}

// Scan phase A: per-block exclusive scan of 1024 counts
__global__ __launch_bounds__(1024) void k_scan1(
    const int* __restrict__ cnt, int* __restrict__ off, int* __restrict__ bsum)
{
    __shared__ int wsum[16];
    const int t = threadIdx.x, lane = t & 63, w = t >> 6;
    const int i = blockIdx.x * 1024 + t;
    const int v = (i < N_ROWS) ? cnt[i] : 0;
    int s = v;
    #pragma unroll
    for (int d = 1; d < 64; d <<= 1) {
        const int u = __shfl_up(s, d);
        if (lane >= d) s += u;
    }
    if (lane == 63) wsum[w] = s;
    __syncthreads();
    if (w == 0 && lane < 16) {
        int ws = wsum[lane];
        #pragma unroll
        for (int d = 1; d < 16; d <<= 1) {
            const int u = __shfl_up(ws, d);
            if (lane >= d) ws += u;
        }
        wsum[lane] = ws;
    }
    __syncthreads();
    const int wprev = (w == 0) ? 0 : wsum[w - 1];
    if (i < N_ROWS) off[i] = wprev + s - v;
    if (t == 0) bsum[blockIdx.x] = wsum[15];
}

// Scan phase B: single small block scans 118 block sums
__global__ __launch_bounds__(128) void k_scan2(
    const int* __restrict__ bsum, int* __restrict__ boff, int nblk)
{
    __shared__ int tmp[2];
    const int t = threadIdx.x, lane = t & 63, w = t >> 6;
    const int v = (t < nblk) ? bsum[t] : 0;
    int s = v;
    #pragma unroll
    for (int d = 1; d < 64; d <<= 1) {
        const int u = __shfl_up(s, d);
        if (lane >= d) s += u;
    }
    if (lane == 63) tmp[w] = s;
    __syncthreads();
    const int add = (w == 1) ? tmp[0] : 0;
    if (t < nblk) boff[t] = add + s - v;
}

// Scan phase C: off[i] += boff[b]; cur[i] = off[i]
__global__ __launch_bounds__(1024) void k_scan3(
    int* __restrict__ off, int* __restrict__ cur, const int* __restrict__ boff)
{
    const int i = blockIdx.x * 1024 + threadIdx.x;
    if (i < N_ROWS) {
        const int o = off[i] + boff[blockIdx.x];
        off[i] = o;
        cur[i] = o;
    }
    if (i == 0) off[N_ROWS] = M_P * E_EDGES;
}

// Phase 3: fill bins — 4 edges/thread ILP; binned16[pos] = dst (ushort, m implied by row)
__global__ __launch_bounds__(256) void k_fill(
    const int* __restrict__ ei, int* __restrict__ cur, unsigned short* __restrict__ binned16)
{
    const int base = blockIdx.x * 1024 + threadIdx.x;
    int rows[4], dsts[4];
    #pragma unroll
    for (int i = 0; i < 4; ++i) {
        const int g = base + i * 256;                   // coalesced per i
        const int m = g / E_EDGES;
        const int e = g - m * E_EDGES;
        rows[i] = m * N_NODES + ei[(m * 2) * E_EDGES + e];
        dsts[i] = ei[(m * 2 + 1) * E_EDGES + e];
    }
    int pos[4];
    #pragma unroll
    for (int i = 0; i < 4; ++i) pos[i] = atomicAdd(&cur[rows[i]], 1);
    #pragma unroll
    for (int i = 0; i < 4; ++i) binned16[pos[i]] = (unsigned short)dsts[i];
}

// Phase 4: gather-reduce — one wave per (m,src) row; lane = feature
__global__ __launch_bounds__(256) void k_gather(
    const int* __restrict__ off, const unsigned short* __restrict__ binned16,
    const float* __restrict__ y, float* __restrict__ aggh)
{
    const int w = threadIdx.x >> 6, lane = threadIdx.x & 63;
    const int row = blockIdx.x * 4 + w;                 // < N_ROWS
    const int m = row / N_NODES;
    const float* ym = y + (size_t)m * N_NODES * 64;
    const int beg = off[row], end = off[row + 1];
    float acc = 0.f;
    for (int i = beg; i < end; i += 64) {
        int idx = 0;
        if (i + lane < end) idx = binned16[i + lane];   // coalesced, 1 load / 64 edges
        const int cn = min(64, end - i);
        for (int j = 0; j < cn; ++j) {
            const int r = __shfl(idx, j);               // broadcast dst
            acc += ym[r * 64 + lane];                   // 256 B contiguous, L3-resident
        }
    }
    aggh[row * 64 + lane] = acc;
}

// ===================== Kernel 3: e[n][m][:] = (relu(aggh+z) @ Wo^T + bo) * mpw[m] =====================
__global__ __launch_bounds__(256) void k_emb(
    const float* __restrict__ aggh, const float* __restrict__ z,
    const float* __restrict__ Wo, const float* __restrict__ bo,
    const float* __restrict__ mpw, float* __restrict__ e)
{
    __shared__ float hT[64][20];
    __shared__ float WoT[64][64];
    const int t = threadIdx.x;
    const int node0 = blockIdx.x * 16;

    for (int m = 0; m < 4; ++m) {
        #pragma unroll
        for (int i = 0; i < 4; ++i) {
            const int o  = (t & 15) + 16 * i;
            const int kq = t >> 4;
            const float4 v = *(const float4*)(Wo + (m * 64 + o) * 64 + kq * 4);
            WoT[kq * 4 + 0][o] = v.x; WoT[kq * 4 + 1][o] = v.y;
            WoT[kq * 4 + 2][o] = v.z; WoT[kq * 4 + 3][o] = v.w;
        }
        {
            const int node = t & 15, kq = t >> 4;
            const int n = node0 + node;
            const float4 a = *(const float4*)(aggh + (m * N_NODES + n) * 64 + kq * 4);
            const float4 b = *(const float4*)(z + (m * N_NODES + n) * 64 + kq * 4);
            hT[kq * 4 + 0][node] = fmaxf(a.x + b.x, 0.f);
            hT[kq * 4 + 1][node] = fmaxf(a.y + b.y, 0.f);
            hT[kq * 4 + 2][node] = fmaxf(a.z + b.z, 0.f);
            hT[kq * 4 + 3][node] = fmaxf(a.w + b.w, 0.f);
        }
        __syncthreads();
        const int o = t & 63, nl4 = (t >> 6) * 4;
        float acc[4] = {};
        #pragma unroll 8
        for (int k = 0; k < 64; ++k) {
            const float bw = WoT[k][o];
            const float4 a = *(const float4*)&hT[k][nl4];
            acc[0] += a.x * bw; acc[1] += a.y * bw; acc[2] += a.z * bw; acc[3] += a.w * bw;
        }
        const float bb = bo[m * 64 + o];
        const float w  = mpw[m];
        #pragma unroll
        for (int i = 0; i < 4; ++i)
            e[((node0 + nl4 + i) * 4 + m) * 64 + o] = (acc[i] + bb) * w;
        __syncthreads();
    }
}

// ===================== Kernel 4: attention via bf16 MFMA (no barriers, per-wave LDS) =====================
__global__ __launch_bounds__(256, 2) void k_attn_mfma(
    const float* __restrict__ e,
    const unsigned short* __restrict__ wqkv_s, const float* __restrict__ tinb,
    const unsigned short* __restrict__ tow_s, const float* __restrict__ tob,
    const float* __restrict__ ln1g, const float* __restrict__ ln1b,
    float* __restrict__ eout, int l)
{
    __shared__ __align__(16) short Xl[8192];      // 16 KB [w][2048]: X B-frags, then O B-frags
    __shared__ __align__(16) short QKV[25600];    // 50 KB [w][tok(32)][200]
    const int t = threadIdx.x;
    const int w = t >> 6, lane = t & 63;
    const int m_ = lane & 15, qc = lane >> 4;
    const int tok0 = blockIdx.x * 128;
    short* Xw = &Xl[w * 2048];
    short* Qw = &QKV[w * 6400];

    #pragma unroll
    for (int i = 0; i < 4; ++i) {
        const int rem = lane + 64 * i;
        const int nt = rem >> 7, h = (rem >> 6) & 1, q = (rem >> 4) & 3, n = rem & 15;
        const int tok = tok0 + w * 32 + nt * 16 + n;
        const int k0 = h * 32 + q * 8;
        float4 a = make_float4(0.f, 0.f, 0.f, 0.f), b = a;
        if (tok < N_TOK) {
            a = *(const float4*)(e + tok * 64 + k0);
            b = *(const float4*)(e + tok * 64 + k0 + 4);
        }
        *(uint4*)&Xw[rem * 8] = make_uint4(pack2bf(a.x, a.y), pack2bf(a.z, a.w),
                                           pack2bf(b.x, b.y), pack2bf(b.z, b.w));
    }

    bf16x8 xb[2][2];
    #pragma unroll
    for (int nt = 0; nt < 2; ++nt)
        #pragma unroll
        for (int h = 0; h < 2; ++h)
            xb[nt][h] = *(const bf16x8*)&Xw[(nt * 2 + h) * 512 + lane * 8];

    const unsigned short* Wq = wqkv_s + l * 12288;
    f32x4 acc[12][2];
    #pragma unroll
    for (int ft = 0; ft < 12; ++ft) {
        const bf16x8 wa0 = *(const bf16x8*)(Wq + (ft * 2 + 0) * 512 + lane * 8);
        const bf16x8 wa1 = *(const bf16x8*)(Wq + (ft * 2 + 1) * 512 + lane * 8);
        const float4 bv = *(const float4*)(tinb + l * 192 + ft * 16 + qc * 4);
        f32x4 c0; c0[0] = bv.x; c0[1] = bv.y; c0[2] = bv.z; c0[3] = bv.w;
        f32x4 c1 = c0;
        c0 = MFMA_B16(wa0, xb[0][0], c0); c0 = MFMA_B16(wa1, xb[0][1], c0);
        c1 = MFMA_B16(wa0, xb[1][0], c1); c1 = MFMA_B16(wa1, xb[1][1], c1);
        acc[ft][0] = c0; acc[ft][1] = c1;
    }
    #pragma unroll
    for (int ft = 0; ft < 12; ++ft)
        #pragma unroll
        for (int nt = 0; nt < 2; ++nt) {
            const int addr = (nt * 16 + m_) * 200 + ft * 16 + qc * 4;
            *(uint2*)&Qw[addr] = make_uint2(pack2bf(acc[ft][nt][0], acc[ft][nt][1]),
                                            pack2bf(acc[ft][nt][2], acc[ft][nt][3]));
        }

    {
        const int node = lane >> 3, head = lane & 7;
        float kk[4][8], vv[4][8];
        #pragma unroll
        for (int j2 = 0; j2 < 4; ++j2) {
            const bf16x8 kr = *(const bf16x8*)&Qw[(node * 4 + j2) * 200 + 64 + head * 8];
            const bf16x8 vr = *(const bf16x8*)&Qw[(node * 4 + j2) * 200 + 128 + head * 8];
            #pragma unroll
            for (int d = 0; d < 8; ++d) { kk[j2][d] = bf2f(kr[d]); vv[j2][d] = bf2f(vr[d]); }
        }
        const float scale = 0.35355339059327373f;
        const int nt = node >> 2, hq = head >> 2, qq = head & 3;
        #pragma unroll
        for (int i = 0; i < 4; ++i) {
            const bf16x8 qr = *(const bf16x8*)&Qw[(node * 4 + i) * 200 + head * 8];
            float q[8];
            #pragma unroll
            for (int d = 0; d < 8; ++d) q[d] = bf2f(qr[d]);
            float s[4];
            #pragma unroll
            for (int j2 = 0; j2 < 4; ++j2) {
                float a2 = 0.f;
                #pragma unroll
                for (int d = 0; d < 8; ++d) a2 += q[d] * kk[j2][d];
                s[j2] = a2 * scale;
            }
            const float mx = fmaxf(fmaxf(s[0], s[1]), fmaxf(s[2], s[3]));
            float p[4], sum = 0.f;
            #pragma unroll
            for (int j2 = 0; j2 < 4; ++j2) { p[j2] = __expf(s[j2] - mx); sum += p[j2]; }
            const float inv = 1.f / sum;
            float o[8];
            #pragma unroll
            for (int d = 0; d < 8; ++d)
                o[d] = (p[0] * vv[0][d] + p[1] * vv[1][d] + p[2] * vv[2][d] + p[3] * vv[3][d]) * inv;
            const int n = (node & 3) * 4 + i;
            *(uint4*)&Xw[(nt * 2 + hq) * 512 + qq * 128 + n * 8] =
                make_uint4(pack2bf(o[0], o[1]), pack2bf(o[2], o[3]),
                           pack2bf(o[4], o[5]), pack2bf(o[6], o[7]));
        }
    }

    bf16x8 ob[2][2];
    #pragma unroll
    for (int nt = 0; nt < 2; ++nt)
        #pragma unroll
        for (int h = 0; h < 2; ++h)
            ob[nt][h] = *(const bf16x8*)&Xw[(nt * 2 + h) * 512 + lane * 8];
    const unsigned short* Tw = tow_s + l * 4096;
    f32x4 acc2[4][2] = {};
    #pragma unroll
    for (int ot = 0; ot < 4; ++ot) {
        const bf16x8 t0 = *(const bf16x8*)(Tw + (ot * 2 + 0) * 512 + lane * 8);
        const bf16x8 t1 = *(const bf16x8*)(Tw + (ot * 2 + 1) * 512 + lane * 8);
        acc2[ot][0] = MFMA_B16(t0, ob[0][0], acc2[ot][0]);
        acc2[ot][0] = MFMA_B16(t1, ob[0][1], acc2[ot][0]);
        acc2[ot][1] = MFMA_B16(t0, ob[1][0], acc2[ot][1]);
        acc2[ot][1] = MFMA_B16(t1, ob[1][1], acc2[ot][1]);
    }

    float4 tbv[4], gv[4], bv2[4];
    #pragma unroll
    for (int ot = 0; ot < 4; ++ot) {
        const int o = l * 64 + ot * 16 + qc * 4;
        tbv[ot] = *(const float4*)(tob + o);
        gv[ot]  = *(const float4*)(ln1g + o);
        bv2[ot] = *(const float4*)(ln1b + o);
    }
    #pragma unroll
    for (int nt = 0; nt < 2; ++nt) {
        const int tok = tok0 + w * 32 + nt * 16 + m_;
        const bool valid = tok < N_TOK;
        float v[4][4];
        float s = 0.f;
        #pragma unroll
        for (int ot = 0; ot < 4; ++ot) {
            float4 rs = make_float4(0.f, 0.f, 0.f, 0.f);
            if (valid) rs = *(const float4*)(e + tok * 64 + ot * 16 + qc * 4);
            v[ot][0] = acc2[ot][nt][0] + tbv[ot].x + rs.x;
            v[ot][1] = acc2[ot][nt][1] + tbv[ot].y + rs.y;
            v[ot][2] = acc2[ot][nt][2] + tbv[ot].z + rs.z;
            v[ot][3] = acc2[ot][nt][3] + tbv[ot].w + rs.w;
            s += v[ot][0] + v[ot][1] + v[ot][2] + v[ot][3];
        }
        s += __shfl_xor(s, 16); s += __shfl_xor(s, 32);
        const float mean = s * (1.f / 64.f);
        float vs = 0.f;
        #pragma unroll
        for (int ot = 0; ot < 4; ++ot)
            #pragma unroll
            for (int r = 0; r < 4; ++r) { v[ot][r] -= mean; vs += v[ot][r] * v[ot][r]; }
        vs += __shfl_xor(vs, 16); vs += __shfl_xor(vs, 32);
        const float rr = rsqrtf(vs * (1.f / 64.f) + LN_EPS);
        if (valid) {
            #pragma unroll
            for (int ot = 0; ot < 4; ++ot) {
                float4 o4 = make_float4(v[ot][0] * rr * gv[ot].x + bv2[ot].x,
                                        v[ot][1] * rr * gv[ot].y + bv2[ot].y,
                                        v[ot][2] * rr * gv[ot].z + bv2[ot].z,
                                        v[ot][3] * rr * gv[ot].w + bv2[ot].w);
                *(float4*)(eout + tok * 64 + ot * 16 + qc * 4) = o4;
            }
        }
    }
}

// ===================== Kernel 4.5: pre-shuffle weights to MFMA-fragment-major bf16 =====================
__global__ __launch_bounds__(256) void k_wshuf(
    const float* __restrict__ ff1w, const float* __restrict__ ff2w,
    const float* __restrict__ tinw, const float* __restrict__ tow,
    unsigned short* __restrict__ w1s, unsigned short* __restrict__ w2s,
    unsigned short* __restrict__ wqkv_s, unsigned short* __restrict__ tow_s)
{
    const int g = blockIdx.x * 256 + threadIdx.x;   // [0, 262144)
    {
        const int l = g >> 17, r2 = g & 131071;
        const int f = r2 >> 6, k = r2 & 63;
        const int c = f >> 6, fc = f & 63, ft = fc >> 4, m = fc & 15;
        const int h = k >> 5, q = (k >> 3) & 3, j = k & 7;
        w1s[l * 131072 + c * 4096 + (ft * 2 + h) * 512 + (q * 16 + m) * 8 + j] = f2bf(ff1w[g]);
    }
    {
        const int l = g >> 17, r2 = g & 131071;
        const int o = r2 >> 11, f = r2 & 2047;
        const int c = f >> 6, fc = f & 63, h = fc >> 5, q = (fc >> 3) & 3, j = fc & 7;
        const int ot = o >> 4, m = o & 15;
        w2s[l * 131072 + c * 4096 + (ot * 2 + h) * 512 + (q * 16 + m) * 8 + j] = f2bf(ff2w[g]);
    }
    if (g < 2 * 192 * 64) {        // qkv in_proj: A-frag, M=f(192), K=64
        const int l = g / 12288, r2 = g - l * 12288;
        const int f = r2 >> 6, k = r2 & 63;
        const int ft = f >> 4, m = f & 15;
        const int h = k >> 5, q = (k >> 3) & 3, j = k & 7;
        wqkv_s[l * 12288 + (ft * 2 + h) * 512 + (q * 16 + m) * 8 + j] = f2bf(tinw[g]);
    }
    if (g < 2 * 64 * 64) {         // out_proj: A-frag, M=o(64), K=64
        const int l = g >> 12, r2 = g & 4095;
        const int o = r2 >> 6, k = r2 & 63;
        const int ot = o >> 4, m = o & 15;
        const int h = k >> 5, q = (k >> 3) & 3, j = k & 7;
        tow_s[l * 4096 + (ot * 2 + h) * 512 + (q * 16 + m) * 8 + j] = f2bf(tow[g]);
    }
}

// ===================== Kernel 5: FFN via bf16 MFMA, single-buffer weights (48 KB LDS, 3 blk/CU) ==========
__global__ __launch_bounds__(256, 3) void k_ffn_mfma(
    const float* __restrict__ e,
    const unsigned short* __restrict__ w1s, const unsigned short* __restrict__ w2s,
    const float* __restrict__ ff1b, const float* __restrict__ ff2b,
    const float* __restrict__ ln2g, const float* __restrict__ ln2b,
    float* __restrict__ eout, int l)
{
    __shared__ __align__(16) short Xl[8192];     // 16 KB
    __shared__ __align__(16) short Act[8192];    // 16 KB
    __shared__ __align__(16) short Wb[8192];     // 16 KB [ W1 4096 | W2 4096 ]
    const int t = threadIdx.x;
    const int w = t >> 6, lane = t & 63;
    const int m_ = lane & 15, qc = lane >> 4;
    const int tok0 = blockIdx.x * 128;

    #pragma unroll
    for (int i = 0; i < 4; ++i) {
        const int g = t + 256 * i;
        const int gw = g >> 8, rem = g & 255;
        const int nt = rem >> 7, h = (rem >> 6) & 1, q = (rem >> 4) & 3, n = rem & 15;
        const int tok = tok0 + gw * 32 + nt * 16 + n;
        const int k = h * 32 + q * 8;
        float4 a = make_float4(0.f, 0.f, 0.f, 0.f), b = a;
        if (tok < N_TOK) {
            a = *(const float4*)(e + tok * 64 + k);
            b = *(const float4*)(e + tok * 64 + k + 4);
        }
        *(uint4*)&Xl[g * 8] = make_uint4(pack2bf(a.x, a.y), pack2bf(a.z, a.w),
                                         pack2bf(b.x, b.y), pack2bf(b.z, b.w));
    }

    const uint4* gw1 = (const uint4*)(w1s + l * 131072);
    const uint4* gw2 = (const uint4*)(w2s + l * 131072);
    uint4 p0 = gw1[t], p1 = gw1[t + 256], p2 = gw2[t], p3 = gw2[t + 256];
    *(uint4*)&Wb[t * 8] = p0;            *(uint4*)&Wb[(t + 256) * 8] = p1;
    *(uint4*)&Wb[4096 + t * 8] = p2;     *(uint4*)&Wb[4096 + (t + 256) * 8] = p3;

    f32x4 acc[4][2] = {};

    for (int c = 0; c < 32; ++c) {
        __syncthreads();            // Wb chunk-c visible
        if (c < 31) {               // issue next chunk's global loads (in flight across compute)
            p0 = gw1[(c + 1) * 512 + t];       p1 = gw1[(c + 1) * 512 + t + 256];
            p2 = gw2[(c + 1) * 512 + t];       p3 = gw2[(c + 1) * 512 + t + 256];
        }
        bf16x8 xb[2][2];
        #pragma unroll
        for (int nt = 0; nt < 2; ++nt)
            #pragma unroll
            for (int h = 0; h < 2; ++h)
                xb[nt][h] = *(const bf16x8*)&Xl[w * 2048 + (nt * 2 + h) * 512 + lane * 8];

        #pragma unroll
        for (int ft = 0; ft < 4; ++ft) {
            const bf16x8 wa0 = *(const bf16x8*)&Wb[(ft * 2 + 0) * 512 + lane * 8];
            const bf16x8 wa1 = *(const bf16x8*)&Wb[(ft * 2 + 1) * 512 + lane * 8];
            const float4 bv = *(const float4*)(ff1b + l * 2048 + c * 64 + ft * 16 + qc * 4);
            f32x4 c0; c0[0] = bv.x; c0[1] = bv.y; c0[2] = bv.z; c0[3] = bv.w;
            f32x4 c1 = c0;
            c0 = MFMA_B16(wa0, xb[0][0], c0); c0 = MFMA_B16(wa1, xb[0][1], c0);
            c1 = MFMA_B16(wa0, xb[1][0], c1); c1 = MFMA_B16(wa1, xb[1][1], c1);
            const int ha = ft >> 1, qa = (ft & 1) * 2 + (qc >> 1), jo = (qc & 1) * 4;
            const int boff = w * 2048 + ha * 512 + qa * 128 + m_ * 8 + jo;
            *(uint2*)&Act[boff] =
                make_uint2(pack2bf(fmaxf(c0[0], 0.f), fmaxf(c0[1], 0.f)),
                           pack2bf(fmaxf(c0[2], 0.f), fmaxf(c0[3], 0.f)));
            *(uint2*)&Act[boff + 1024] =
                make_uint2(pack2bf(fmaxf(c1[0], 0.f), fmaxf(c1[1], 0.f)),
                           pack2bf(fmaxf(c1[2], 0.f), fmaxf(c1[3], 0.f)));
        }
        bf16x8 ab[2][2];
        #pragma unroll
        for (int nt = 0; nt < 2; ++nt)
            #pragma unroll
            for (int h = 0; h < 2; ++h)
                ab[nt][h] = *(const bf16x8*)&Act[w * 2048 + (nt * 2 + h) * 512 + lane * 8];
        #pragma unroll
        for (int ot = 0; ot < 4; ++ot) {
            const bf16x8 w20 = *(const bf16x8*)&Wb[4096 + (ot * 2 + 0) * 512 + lane * 8];
            const bf16x8 w21 = *(const bf16x8*)&Wb[4096 + (ot * 2 + 1) * 512 + lane * 8];
            acc[ot][0] = MFMA_B16(w20, ab[0][0], acc[ot][0]);
            acc[ot][0] = MFMA_B16(w21, ab[0][1], acc[ot][0]);
            acc[ot][1] = MFMA_B16(w20, ab[1][0], acc[ot][1]);
            acc[ot][1] = MFMA_B16(w21, ab[1][1], acc[ot][1]);
        }
        __syncthreads();            // all reads of Wb chunk-c done
        if (c < 31) {
            *(uint4*)&Wb[t * 8] = p0;            *(uint4*)&Wb[(t + 256) * 8] = p1;
            *(uint4*)&Wb[4096 + t * 8] = p2;     *(uint4*)&Wb[4096 + (t + 256) * 8] = p3;
        }
    }

    float4 fb2v[4], gv[4], bv2[4];
    #pragma unroll
    for (int ot = 0; ot < 4; ++ot) {
        const int o = l * 64 + ot * 16 + qc * 4;
        fb2v[ot] = *(const float4*)(ff2b + o);
        gv[ot]   = *(const float4*)(ln2g + o);
        bv2[ot]  = *(const float4*)(ln2b + o);
    }
    #pragma unroll
    for (int nt = 0; nt < 2; ++nt) {
        const int tok = tok0 + w * 32 + nt * 16 + m_;
        const bool valid = tok < N_TOK;
        float v[4][4];
        float s = 0.f;
        #pragma unroll
        for (int ot = 0; ot < 4; ++ot) {
            float4 rs = make_float4(0.f, 0.f, 0.f, 0.f);
            if (valid) rs = *(const float4*)(e + tok * 64 + ot * 16 + qc * 4);
            v[ot][0] = acc[ot][nt][0] + fb2v[ot].x + rs.x;
            v[ot][1] = acc[ot][nt][1] + fb2v[ot].y + rs.y;
            v[ot][2] = acc[ot][nt][2] + fb2v[ot].z + rs.z;
            v[ot][3] = acc[ot][nt][3] + fb2v[ot].w + rs.w;
            s += v[ot][0] + v[ot][1] + v[ot][2] + v[ot][3];
        }
        s += __shfl_xor(s, 16); s += __shfl_xor(s, 32);
        const float mean = s * (1.f / 64.f);
        float vs = 0.f;
        #pragma unroll
        for (int ot = 0; ot < 4; ++ot)
            #pragma unroll
            for (int r = 0; r < 4; ++r) { v[ot][r] -= mean; vs += v[ot][r] * v[ot][r]; }
        vs += __shfl_xor(vs, 16); vs += __shfl_xor(vs, 32);
        const float rr = rsqrtf(vs * (1.f / 64.f) + LN_EPS);
        if (valid) {
            #pragma unroll
            for (int ot = 0; ot < 4; ++ot) {
                float4 o4 = make_float4(v[ot][0] * rr * gv[ot].x + bv2[ot].x,
                                        v[ot][1] * rr * gv[ot].y + bv2[ot].y,
                                        v[ot][2] * rr * gv[ot].z + bv2[ot].z,
                                        v[ot][3] * rr * gv[ot].w + bv2[ot].w);
                *(float4*)(eout + tok * 64 + ot * 16 + qc * 4) = o4;
            }
        }
    }
}

// ===================== Kernel 6: mean-pool + 2-layer regressor =====================
__global__ __launch_bounds__(256) void k_reg(
    const float* __restrict__ e,
    const float* __restrict__ r1w, const float* __restrict__ r1b,
    const float* __restrict__ r2w, const float* __restrict__ r2b,
    float* __restrict__ out)
{
    __shared__ float r1T[64][64];
    __shared__ float pld[4][64];
    const int t = threadIdx.x;
    #pragma unroll
    for (int i = 0; i < 4; ++i) {
        const int j  = (t & 15) + 16 * i;
        const int kq = t >> 4;
        const float4 v = *(const float4*)(r1w + j * 64 + kq * 4);
        r1T[kq * 4 + 0][j] = v.x; r1T[kq * 4 + 1][j] = v.y;
        r1T[kq * 4 + 2][j] = v.z; r1T[kq * 4 + 3][j] = v.w;
    }
    const int w = t >> 6, lane = t & 63;
    const int n = blockIdx.x * 4 + w;
    const float p = 0.25f * (e[(n * 4 + 0) * 64 + lane] + e[(n * 4 + 1) * 64 + lane] +
                             e[(n * 4 + 2) * 64 + lane] + e[(n * 4 + 3) * 64 + lane]);
    pld[w][lane] = p;
    __syncthreads();
    float acc = r1b[lane];
    #pragma unroll 8
    for (int k = 0; k < 64; ++k) acc += pld[w][k] * r1T[k][lane];
    acc = fmaxf(acc, 0.f);
    float partial = acc * r2w[lane];
    partial += __shfl_xor(partial, 1);  partial += __shfl_xor(partial, 2);
    partial += __shfl_xor(partial, 4);  partial += __shfl_xor(partial, 8);
    partial += __shfl_xor(partial, 16); partial += __shfl_xor(partial, 32);
    if (lane == 0) out[n] = partial + r2b[0];
}

// ===================== host launcher =====================
extern "C" void kernel_launch(void* const* d_in, const int* in_sizes, int n_in,
                              void* d_out, int out_size, void* d_ws, size_t ws_size,
                              hipStream_t stream) {
    const float* x    = (const float*)d_in[0];
    const int*   ei   = (const int*)d_in[1];
    const float* mpw  = (const float*)d_in[2];
    const float* W0   = (const float*)d_in[3];
    const float* b0   = (const float*)d_in[4];
    const float* Wl   = (const float*)d_in[5];
    const float* bl   = (const float*)d_in[6];
    const float* W1   = (const float*)d_in[7];
    const float* b1   = (const float*)d_in[8];
    const float* Wo   = (const float*)d_in[9];
    const float* bo   = (const float*)d_in[10];
    const float* tinw = (const float*)d_in[11];
    const float* tinb = (const float*)d_in[12];
    const float* tow  = (const float*)d_in[13];
    const float* tob  = (const float*)d_in[14];
    const float* ln1g = (const float*)d_in[15];
    const float* ln1b = (const float*)d_in[16];
    const float* ff1w = (const float*)d_in[17];
    const float* ff1b = (const float*)d_in[18];
    const float* ff2w = (const float*)d_in[19];
    const float* ff2b = (const float*)d_in[20];
    const float* ln2g = (const float*)d_in[21];
    const float* ln2b = (const float*)d_in[22];
    const float* r1w  = (const float*)d_in[23];
    const float* r1b  = (const float*)d_in[24];
    const float* r2w  = (const float*)d_in[25];
    const float* r2b  = (const float*)d_in[26];

    const size_t CH = (size_t)M_P * N_NODES * 64;
    float* y    = (float*)d_ws;
    float* zz   = y + CH;
    float* aggh = zz + CH;
    float* e    = aggh + CH;
    // y region is dead after k_gather — reuse for shuffled bf16 weights
    unsigned short* w1s    = (unsigned short*)y;
    unsigned short* w2s    = w1s + 262144;
    unsigned short* wqkv_s = w2s + 262144;
    unsigned short* tow_s  = wqkv_s + 24576;
    // e region is dead until k_emb — host the binning temporaries there
    int* off                   = (int*)e;                         // N_ROWS+1
    int* cur                   = off + (N_ROWS + 1);              // N_ROWS
    unsigned short* binned16   = (unsigned short*)(cur + N_ROWS); // M*E ushorts
    int* bsum                  = (int*)(binned16 + M_P * E_EDGES);
    int* boff                  = bsum + 128;

    const int SCAN_BLKS = (N_ROWS + 1023) / 1024;   // 118

    hipMemsetAsync(cur, 0, N_ROWS * sizeof(int), stream);
    k_lin_yz<<<dim3(469, 8), 256, 0, stream>>>(x, W0, b0, Wl, bl, W1, b1, y, zz);
    k_hist<<<(M_P * E_EDGES) / 1024, 256, 0, stream>>>(ei, cur);
    k_scan1<<<SCAN_BLKS, 1024, 0, stream>>>(cur, off, bsum);
    k_scan2<<<1, 128, 0, stream>>>(bsum, boff, SCAN_BLKS);
    k_scan3<<<SCAN_BLKS, 1024, 0, stream>>>(off, cur, boff);
    k_fill<<<(M_P * E_EDGES) / 1024, 256, 0, stream>>>(ei, cur, binned16);
    k_gather<<<N_ROWS / 4, 256, 0, stream>>>(off, binned16, y, aggh);
    k_emb<<<N_NODES / 16, 256, 0, stream>>>(aggh, zz, Wo, bo, mpw, e);
    k_wshuf<<<1024, 256, 0, stream>>>(ff1w, ff2w, tinw, tow, w1s, w2s, wqkv_s, tow_s);
    for (int l = 0; l < 2; ++l) {
        k_attn_mfma<<<(N_TOK + 127) / 128, 256, 0, stream>>>(e, wqkv_s, tinb, tow_s, tob,
                                                             ln1g, ln1b, e, l);
        k_ffn_mfma<<<(N_TOK + 127) / 128, 256, 0, stream>>>(e, w1s, w2s, ff1b, ff2b,
                                                            ln2g, ln2b, e, l);
    }
    k_reg<<<N_NODES / 4, 256, 0, stream>>>(e, r1w, r1b, r2w, r2b, (float*)d_out);
}

// Round 6
// 765.817 us; speedup vs baseline: 1.5885x; 1.0837x over previous
//
#include <hip/hip_runtime.h>
#include <hip/hip_bf16.h>
#include <math.h>

#define N_NODES 30000
#define M_P     4
#define E_EDGES 480000
#define N_TOK   (N_NODES * 4)
#define N_ROWS  (M_P * N_NODES)      // 120000 (m,src) rows
#define CAP     64                   // bin capacity; Poisson(16) max over 120k rows ~36
#define LN_EPS  1e-5f

typedef short bf16x8 __attribute__((ext_vector_type(8)));
typedef float f32x4  __attribute__((ext_vector_type(4)));
#define MFMA_B16(a, b, c) __builtin_amdgcn_mfma_f32_16x16x32_bf16(a, b, c, 0, 0, 0)

__device__ inline unsigned short f2bf(float f) {
    union { float f; unsigned u; } v; v.f = f;
    unsigned r = v.u + 0x7fffu + ((v.u >> 16) & 1u);
    return (unsigned short)(r >> 16);
}
// HW packed cvt (v_cvt_pk_bf16_f32, RNE — same rounding as f2bf)
__device__ inline unsigned pack2bf(float a, float b) {
    union { __hip_bfloat162 h; unsigned u; } cv;
    cv.h = __float22bfloat162_rn(make_float2(a, b));
    return cv.u;
}
__device__ inline float bf2f(short s) {
    union { unsigned u; float f; } v; v.u = ((unsigned)(unsigned short)s) << 16;
    return v.f;
}

// ===================== Kernel 1: y = x@Wl^T ; z = x@(W0+W1)^T + (b0+b1+bl) =====================
__global__ __launch_bounds__(256, 2) void k_lin_yz(
    const float* __restrict__ x,
    const float* __restrict__ W0, const float* __restrict__ b0,
    const float* __restrict__ Wl, const float* __restrict__ bl,
    const float* __restrict__ W1, const float* __restrict__ b1,
    float* __restrict__ y, float* __restrict__ z)
{
    __shared__ float xT[128][68];   // [k][node]
    __shared__ float wT[128][68];   // [k][h]
    const int t     = threadIdx.x;
    const int m     = blockIdx.y >> 1;
    const int which = blockIdx.y & 1;
    const int node0 = blockIdx.x * 64;

    #pragma unroll
    for (int i = 0; i < 8; ++i) {
        const int node = (t & 31) + 32 * (i & 1);
        const int kq   = (t >> 5) + 8 * (i >> 1);
        float4 v = make_float4(0.f, 0.f, 0.f, 0.f);
        const int n = node0 + node;
        if (n < N_NODES) v = *(const float4*)(x + n * 128 + kq * 4);
        xT[kq * 4 + 0][node] = v.x; xT[kq * 4 + 1][node] = v.y;
        xT[kq * 4 + 2][node] = v.z; xT[kq * 4 + 3][node] = v.w;
    }
    #pragma unroll
    for (int i = 0; i < 8; ++i) {
        const int h  = (t & 31) + 32 * (i & 1);
        const int kq = (t >> 5) + 8 * (i >> 1);
        float4 v;
        if (which) {
            v = *(const float4*)(W0 + (m * 64 + h) * 128 + kq * 4);
            const float4 v2 = *(const float4*)(W1 + (m * 64 + h) * 128 + kq * 4);
            v.x += v2.x; v.y += v2.y; v.z += v2.z; v.w += v2.w;
        } else {
            v = *(const float4*)(Wl + (m * 64 + h) * 128 + kq * 4);
        }
        wT[kq * 4 + 0][h] = v.x; wT[kq * 4 + 1][h] = v.y;
        wT[kq * 4 + 2][h] = v.z; wT[kq * 4 + 3][h] = v.w;
    }
    __syncthreads();

    const int tx = t & 15, ty = t >> 4;
    const int hb = tx * 4, nb = ty * 4;
    float acc[4][4] = {};
    #pragma unroll 8
    for (int k = 0; k < 128; ++k) {
        const float4 a = *(const float4*)&xT[k][nb];
        const float4 b = *(const float4*)&wT[k][hb];
        acc[0][0] += a.x * b.x; acc[0][1] += a.x * b.y; acc[0][2] += a.x * b.z; acc[0][3] += a.x * b.w;
        acc[1][0] += a.y * b.x; acc[1][1] += a.y * b.y; acc[1][2] += a.y * b.z; acc[1][3] += a.y * b.w;
        acc[2][0] += a.z * b.x; acc[2][1] += a.z * b.y; acc[2][2] += a.z * b.z; acc[2][3] += a.z * b.w;
        acc[3][0] += a.w * b.x; acc[3][1] += a.w * b.y; acc[3][2] += a.w * b.z; acc[3][3] += a.w * b.w;
    }
    float bias[4] = {0.f, 0.f, 0.f, 0.f};
    if (which) {
        #pragma unroll
        for (int j = 0; j < 4; ++j)
            bias[j] = b0[m * 64 + hb + j] + b1[m * 64 + hb + j] + bl[m * 64 + hb + j];
    }
    float* outp = which ? z : y;
    #pragma unroll
    for (int i = 0; i < 4; ++i) {
        const int n = node0 + nb + i;
        if (n < N_NODES) {
            float4 v = make_float4(acc[i][0] + bias[0], acc[i][1] + bias[1],
                                   acc[i][2] + bias[2], acc[i][3] + bias[3]);
            *(float4*)(outp + (m * N_NODES + n) * 64 + hb) = v;
        }
    }
}

// ===================== Capacity-binning scatter replacement (no hist/scan) =====================
// binned16[row*CAP + pos] = dst; pos from per-row cursor. Overflow (never in practice,
// Poisson(16) vs CAP=64) falls back to fp32 atomics into pre-zeroed aggh.
__global__ __launch_bounds__(256) void k_fill(
    const int* __restrict__ ei, int* __restrict__ cur,
    unsigned short* __restrict__ binned16,
    const float* __restrict__ y, float* __restrict__ aggh)
{
    const int base = blockIdx.x * 2048 + threadIdx.x;   // 8 edges/thread
    int rows[8], dsts[8];
    #pragma unroll
    for (int i = 0; i < 8; ++i) {
        const int g = base + i * 256;                   // coalesced per i
        rows[i] = -1;
        if (g < M_P * E_EDGES) {
            const int m = g / E_EDGES;
            const int e = g - m * E_EDGES;
            rows[i] = m * N_NODES + ei[(m * 2) * E_EDGES + e];
            dsts[i] = ei[(m * 2 + 1) * E_EDGES + e];
        }
    }
    int pos[8];
    #pragma unroll
    for (int i = 0; i < 8; ++i)
        if (rows[i] >= 0) pos[i] = atomicAdd(&cur[rows[i]], 1);
    #pragma unroll
    for (int i = 0; i < 8; ++i) {
        if (rows[i] >= 0) {
            if (pos[i] < CAP) {
                binned16[rows[i] * CAP + pos[i]] = (unsigned short)dsts[i];
            } else {                                    // safety net, statistically never taken
                const int m = rows[i] / N_NODES;
                const float* yr = y + ((size_t)m * N_NODES + dsts[i]) * 64;
                for (int f = 0; f < 64; ++f)
                    unsafeAtomicAdd(&aggh[(size_t)rows[i] * 64 + f], yr[f]);
            }
        }
    }
}

// Gather-reduce — one wave per (m,src) row; lane = feature
__global__ __launch_bounds__(256) void k_gather(
    const int* __restrict__ cur, const unsigned short* __restrict__ binned16,
    const float* __restrict__ y, float* __restrict__ aggh)
{
    const int w = threadIdx.x >> 6, lane = threadIdx.x & 63;
    const int row = blockIdx.x * 4 + w;                 // < N_ROWS
    const int m = row / N_NODES;
    const float* ym = y + (size_t)m * N_NODES * 64;
    const int tot = cur[row];
    const int cnt = min(tot, CAP);
    float acc = (tot > CAP) ? aggh[row * 64 + lane] : 0.f;  // overflow contributions
    int idx = 0;
    if (lane < cnt) idx = binned16[row * CAP + lane];   // one coalesced 128 B slab
    for (int j = 0; j < cnt; ++j) {
        const int r = __shfl(idx, j);                   // broadcast dst
        acc += ym[r * 64 + lane];                       // 256 B contiguous, L3-resident
    }
    aggh[row * 64 + lane] = acc;
}

// ===================== Kernel 3: e[n][m][:] = (relu(aggh+z) @ Wo^T + bo) * mpw[m] =====================
__global__ __launch_bounds__(256) void k_emb(
    const float* __restrict__ aggh, const float* __restrict__ z,
    const float* __restrict__ Wo, const float* __restrict__ bo,
    const float* __restrict__ mpw, float* __restrict__ e)
{
    __shared__ float hT[64][20];
    __shared__ float WoT[64][64];
    const int t = threadIdx.x;
    const int node0 = blockIdx.x * 16;

    for (int m = 0; m < 4; ++m) {
        #pragma unroll
        for (int i = 0; i < 4; ++i) {
            const int o  = (t & 15) + 16 * i;
            const int kq = t >> 4;
            const float4 v = *(const float4*)(Wo + (m * 64 + o) * 64 + kq * 4);
            WoT[kq * 4 + 0][o] = v.x; WoT[kq * 4 + 1][o] = v.y;
            WoT[kq * 4 + 2][o] = v.z; WoT[kq * 4 + 3][o] = v.w;
        }
        {
            const int node = t & 15, kq = t >> 4;
            const int n = node0 + node;
            const float4 a = *(const float4*)(aggh + (m * N_NODES + n) * 64 + kq * 4);
            const float4 b = *(const float4*)(z + (m * N_NODES + n) * 64 + kq * 4);
            hT[kq * 4 + 0][node] = fmaxf(a.x + b.x, 0.f);
            hT[kq * 4 + 1][node] = fmaxf(a.y + b.y, 0.f);
            hT[kq * 4 + 2][node] = fmaxf(a.z + b.z, 0.f);
            hT[kq * 4 + 3][node] = fmaxf(a.w + b.w, 0.f);
        }
        __syncthreads();
        const int o = t & 63, nl4 = (t >> 6) * 4;
        float acc[4] = {};
        #pragma unroll 8
        for (int k = 0; k < 64; ++k) {
            const float bw = WoT[k][o];
            const float4 a = *(const float4*)&hT[k][nl4];
            acc[0] += a.x * bw; acc[1] += a.y * bw; acc[2] += a.z * bw; acc[3] += a.w * bw;
        }
        const float bb = bo[m * 64 + o];
        const float w  = mpw[m];
        #pragma unroll
        for (int i = 0; i < 4; ++i)
            e[((node0 + nl4 + i) * 4 + m) * 64 + o] = (acc[i] + bb) * w;
        __syncthreads();
    }
}

// ===================== Kernel 4: attention via bf16 MFMA (no barriers, per-wave LDS) =====================
__global__ __launch_bounds__(256, 2) void k_attn_mfma(
    const float* __restrict__ e,
    const unsigned short* __restrict__ wqkv_s, const float* __restrict__ tinb,
    const unsigned short* __restrict__ tow_s, const float* __restrict__ tob,
    const float* __restrict__ ln1g, const float* __restrict__ ln1b,
    float* __restrict__ eout, int l)
{
    __shared__ __align__(16) short Xl[8192];      // 16 KB [w][2048]: X B-frags, then O B-frags
    __shared__ __align__(16) short QKV[25600];    // 50 KB [w][tok(32)][200]
    const int t = threadIdx.x;
    const int w = t >> 6, lane = t & 63;
    const int m_ = lane & 15, qc = lane >> 4;
    const int tok0 = blockIdx.x * 128;
    short* Xw = &Xl[w * 2048];
    short* Qw = &QKV[w * 6400];

    #pragma unroll
    for (int i = 0; i < 4; ++i) {
        const int rem = lane + 64 * i;
        const int nt = rem >> 7, h = (rem >> 6) & 1, q = (rem >> 4) & 3, n = rem & 15;
        const int tok = tok0 + w * 32 + nt * 16 + n;
        const int k0 = h * 32 + q * 8;
        float4 a = make_float4(0.f, 0.f, 0.f, 0.f), b = a;
        if (tok < N_TOK) {
            a = *(const float4*)(e + tok * 64 + k0);
            b = *(const float4*)(e + tok * 64 + k0 + 4);
        }
        *(uint4*)&Xw[rem * 8] = make_uint4(pack2bf(a.x, a.y), pack2bf(a.z, a.w),
                                           pack2bf(b.x, b.y), pack2bf(b.z, b.w));
    }

    bf16x8 xb[2][2];
    #pragma unroll
    for (int nt = 0; nt < 2; ++nt)
        #pragma unroll
        for (int h = 0; h < 2; ++h)
            xb[nt][h] = *(const bf16x8*)&Xw[(nt * 2 + h) * 512 + lane * 8];

    const unsigned short* Wq = wqkv_s + l * 12288;
    f32x4 acc[12][2];
    #pragma unroll
    for (int ft = 0; ft < 12; ++ft) {
        const bf16x8 wa0 = *(const bf16x8*)(Wq + (ft * 2 + 0) * 512 + lane * 8);
        const bf16x8 wa1 = *(const bf16x8*)(Wq + (ft * 2 + 1) * 512 + lane * 8);
        const float4 bv = *(const float4*)(tinb + l * 192 + ft * 16 + qc * 4);
        f32x4 c0; c0[0] = bv.x; c0[1] = bv.y; c0[2] = bv.z; c0[3] = bv.w;
        f32x4 c1 = c0;
        c0 = MFMA_B16(wa0, xb[0][0], c0); c0 = MFMA_B16(wa1, xb[0][1], c0);
        c1 = MFMA_B16(wa0, xb[1][0], c1); c1 = MFMA_B16(wa1, xb[1][1], c1);
        acc[ft][0] = c0; acc[ft][1] = c1;
    }
    #pragma unroll
    for (int ft = 0; ft < 12; ++ft)
        #pragma unroll
        for (int nt = 0; nt < 2; ++nt) {
            const int addr = (nt * 16 + m_) * 200 + ft * 16 + qc * 4;
            *(uint2*)&Qw[addr] = make_uint2(pack2bf(acc[ft][nt][0], acc[ft][nt][1]),
                                            pack2bf(acc[ft][nt][2], acc[ft][nt][3]));
        }

    {
        const int node = lane >> 3, head = lane & 7;
        float kk[4][8], vv[4][8];
        #pragma unroll
        for (int j2 = 0; j2 < 4; ++j2) {
            const bf16x8 kr = *(const bf16x8*)&Qw[(node * 4 + j2) * 200 + 64 + head * 8];
            const bf16x8 vr = *(const bf16x8*)&Qw[(node * 4 + j2) * 200 + 128 + head * 8];
            #pragma unroll
            for (int d = 0; d < 8; ++d) { kk[j2][d] = bf2f(kr[d]); vv[j2][d] = bf2f(vr[d]); }
        }
        const float scale = 0.35355339059327373f;
        const int nt = node >> 2, hq = head >> 2, qq = head & 3;
        #pragma unroll
        for (int i = 0; i < 4; ++i) {
            const bf16x8 qr = *(const bf16x8*)&Qw[(node * 4 + i) * 200 + head * 8];
            float q[8];
            #pragma unroll
            for (int d = 0; d < 8; ++d) q[d] = bf2f(qr[d]);
            float s[4];
            #pragma unroll
            for (int j2 = 0; j2 < 4; ++j2) {
                float a2 = 0.f;
                #pragma unroll
                for (int d = 0; d < 8; ++d) a2 += q[d] * kk[j2][d];
                s[j2] = a2 * scale;
            }
            const float mx = fmaxf(fmaxf(s[0], s[1]), fmaxf(s[2], s[3]));
            float p[4], sum = 0.f;
            #pragma unroll
            for (int j2 = 0; j2 < 4; ++j2) { p[j2] = __expf(s[j2] - mx); sum += p[j2]; }
            const float inv = 1.f / sum;
            float o[8];
            #pragma unroll
            for (int d = 0; d < 8; ++d)
                o[d] = (p[0] * vv[0][d] + p[1] * vv[1][d] + p[2] * vv[2][d] + p[3] * vv[3][d]) * inv;
            const int n = (node & 3) * 4 + i;
            *(uint4*)&Xw[(nt * 2 + hq) * 512 + qq * 128 + n * 8] =
                make_uint4(pack2bf(o[0], o[1]), pack2bf(o[2], o[3]),
                           pack2bf(o[4], o[5]), pack2bf(o[6], o[7]));
        }
    }

    bf16x8 ob[2][2];
    #pragma unroll
    for (int nt = 0; nt < 2; ++nt)
        #pragma unroll
        for (int h = 0; h < 2; ++h)
            ob[nt][h] = *(const bf16x8*)&Xw[(nt * 2 + h) * 512 + lane * 8];
    const unsigned short* Tw = tow_s + l * 4096;
    f32x4 acc2[4][2] = {};
    #pragma unroll
    for (int ot = 0; ot < 4; ++ot) {
        const bf16x8 t0 = *(const bf16x8*)(Tw + (ot * 2 + 0) * 512 + lane * 8);
        const bf16x8 t1 = *(const bf16x8*)(Tw + (ot * 2 + 1) * 512 + lane * 8);
        acc2[ot][0] = MFMA_B16(t0, ob[0][0], acc2[ot][0]);
        acc2[ot][0] = MFMA_B16(t1, ob[0][1], acc2[ot][0]);
        acc2[ot][1] = MFMA_B16(t0, ob[1][0], acc2[ot][1]);
        acc2[ot][1] = MFMA_B16(t1, ob[1][1], acc2[ot][1]);
    }

    float4 tbv[4], gv[4], bv2[4];
    #pragma unroll
    for (int ot = 0; ot < 4; ++ot) {
        const int o = l * 64 + ot * 16 + qc * 4;
        tbv[ot] = *(const float4*)(tob + o);
        gv[ot]  = *(const float4*)(ln1g + o);
        bv2[ot] = *(const float4*)(ln1b + o);
    }
    #pragma unroll
    for (int nt = 0; nt < 2; ++nt) {
        const int tok = tok0 + w * 32 + nt * 16 + m_;
        const bool valid = tok < N_TOK;
        float v[4][4];
        float s = 0.f;
        #pragma unroll
        for (int ot = 0; ot < 4; ++ot) {
            float4 rs = make_float4(0.f, 0.f, 0.f, 0.f);
            if (valid) rs = *(const float4*)(e + tok * 64 + ot * 16 + qc * 4);
            v[ot][0] = acc2[ot][nt][0] + tbv[ot].x + rs.x;
            v[ot][1] = acc2[ot][nt][1] + tbv[ot].y + rs.y;
            v[ot][2] = acc2[ot][nt][2] + tbv[ot].z + rs.z;
            v[ot][3] = acc2[ot][nt][3] + tbv[ot].w + rs.w;
            s += v[ot][0] + v[ot][1] + v[ot][2] + v[ot][3];
        }
        s += __shfl_xor(s, 16); s += __shfl_xor(s, 32);
        const float mean = s * (1.f / 64.f);
        float vs = 0.f;
        #pragma unroll
        for (int ot = 0; ot < 4; ++ot)
            #pragma unroll
            for (int r = 0; r < 4; ++r) { v[ot][r] -= mean; vs += v[ot][r] * v[ot][r]; }
        vs += __shfl_xor(vs, 16); vs += __shfl_xor(vs, 32);
        const float rr = rsqrtf(vs * (1.f / 64.f) + LN_EPS);
        if (valid) {
            #pragma unroll
            for (int ot = 0; ot < 4; ++ot) {
                float4 o4 = make_float4(v[ot][0] * rr * gv[ot].x + bv2[ot].x,
                                        v[ot][1] * rr * gv[ot].y + bv2[ot].y,
                                        v[ot][2] * rr * gv[ot].z + bv2[ot].z,
                                        v[ot][3] * rr * gv[ot].w + bv2[ot].w);
                *(float4*)(eout + tok * 64 + ot * 16 + qc * 4) = o4;
            }
        }
    }
}

// ===================== Kernel 4.5: pre-shuffle weights to MFMA-fragment-major bf16 =====================
__global__ __launch_bounds__(256) void k_wshuf(
    const float* __restrict__ ff1w, const float* __restrict__ ff2w,
    const float* __restrict__ tinw, const float* __restrict__ tow,
    unsigned short* __restrict__ w1s, unsigned short* __restrict__ w2s,
    unsigned short* __restrict__ wqkv_s, unsigned short* __restrict__ tow_s)
{
    const int g = blockIdx.x * 256 + threadIdx.x;   // [0, 262144)
    {
        const int l = g >> 17, r2 = g & 131071;
        const int f = r2 >> 6, k = r2 & 63;
        const int c = f >> 6, fc = f & 63, ft = fc >> 4, m = fc & 15;
        const int h = k >> 5, q = (k >> 3) & 3, j = k & 7;
        w1s[l * 131072 + c * 4096 + (ft * 2 + h) * 512 + (q * 16 + m) * 8 + j] = f2bf(ff1w[g]);
    }
    {
        const int l = g >> 17, r2 = g & 131071;
        const int o = r2 >> 11, f = r2 & 2047;
        const int c = f >> 6, fc = f & 63, h = fc >> 5, q = (fc >> 3) & 3, j = fc & 7;
        const int ot = o >> 4, m = o & 15;
        w2s[l * 131072 + c * 4096 + (ot * 2 + h) * 512 + (q * 16 + m) * 8 + j] = f2bf(ff2w[g]);
    }
    if (g < 2 * 192 * 64) {        // qkv in_proj: A-frag, M=f(192), K=64
        const int l = g / 12288, r2 = g - l * 12288;
        const int f = r2 >> 6, k = r2 & 63;
        const int ft = f >> 4, m = f & 15;
        const int h = k >> 5, q = (k >> 3) & 3, j = k & 7;
        wqkv_s[l * 12288 + (ft * 2 + h) * 512 + (q * 16 + m) * 8 + j] = f2bf(tinw[g]);
    }
    if (g < 2 * 64 * 64) {         // out_proj: A-frag, M=o(64), K=64
        const int l = g >> 12, r2 = g & 4095;
        const int o = r2 >> 6, k = r2 & 63;
        const int ot = o >> 4, m = o & 15;
        const int h = k >> 5, q = (k >> 3) & 3, j = k & 7;
        tow_s[l * 4096 + (ot * 2 + h) * 512 + (q * 16 + m) * 8 + j] = f2bf(tow[g]);
    }
}

// ===================== Kernel 5: FFN via bf16 MFMA, single-buffer weights (48 KB LDS, 3 blk/CU) ==========
__global__ __launch_bounds__(256, 3) void k_ffn_mfma(
    const float* __restrict__ e,
    const unsigned short* __restrict__ w1s, const unsigned short* __restrict__ w2s,
    const float* __restrict__ ff1b, const float* __restrict__ ff2b,
    const float* __restrict__ ln2g, const float* __restrict__ ln2b,
    float* __restrict__ eout, int l)
{
    __shared__ __align__(16) short Xl[8192];     // 16 KB
    __shared__ __align__(16) short Act[8192];    // 16 KB
    __shared__ __align__(16) short Wb[8192];     // 16 KB [ W1 4096 | W2 4096 ]
    const int t = threadIdx.x;
    const int w = t >> 6, lane = t & 63;
    const int m_ = lane & 15, qc = lane >> 4;
    const int tok0 = blockIdx.x * 128;

    #pragma unroll
    for (int i = 0; i < 4; ++i) {
        const int g = t + 256 * i;
        const int gw = g >> 8, rem = g & 255;
        const int nt = rem >> 7, h = (rem >> 6) & 1, q = (rem >> 4) & 3, n = rem & 15;
        const int tok = tok0 + gw * 32 + nt * 16 + n;
        const int k = h * 32 + q * 8;
        float4 a = make_float4(0.f, 0.f, 0.f, 0.f), b = a;
        if (tok < N_TOK) {
            a = *(const float4*)(e + tok * 64 + k);
            b = *(const float4*)(e + tok * 64 + k + 4);
        }
        *(uint4*)&Xl[g * 8] = make_uint4(pack2bf(a.x, a.y), pack2bf(a.z, a.w),
                                         pack2bf(b.x, b.y), pack2bf(b.z, b.w));
    }

    const uint4* gw1 = (const uint4*)(w1s + l * 131072);
    const uint4* gw2 = (const uint4*)(w2s + l * 131072);
    uint4 p0 = gw1[t], p1 = gw1[t + 256], p2 = gw2[t], p3 = gw2[t + 256];
    *(uint4*)&Wb[t * 8] = p0;            *(uint4*)&Wb[(t + 256) * 8] = p1;
    *(uint4*)&Wb[4096 + t * 8] = p2;     *(uint4*)&Wb[4096 + (t + 256) * 8] = p3;

    f32x4 acc[4][2] = {};

    for (int c = 0; c < 32; ++c) {
        __syncthreads();            // Wb chunk-c visible
        if (c < 31) {               // issue next chunk's global loads (in flight across compute)
            p0 = gw1[(c + 1) * 512 + t];       p1 = gw1[(c + 1) * 512 + t + 256];
            p2 = gw2[(c + 1) * 512 + t];       p3 = gw2[(c + 1) * 512 + t + 256];
        }
        bf16x8 xb[2][2];
        #pragma unroll
        for (int nt = 0; nt < 2; ++nt)
            #pragma unroll
            for (int h = 0; h < 2; ++h)
                xb[nt][h] = *(const bf16x8*)&Xl[w * 2048 + (nt * 2 + h) * 512 + lane * 8];

        #pragma unroll
        for (int ft = 0; ft < 4; ++ft) {
            const bf16x8 wa0 = *(const bf16x8*)&Wb[(ft * 2 + 0) * 512 + lane * 8];
            const bf16x8 wa1 = *(const bf16x8*)&Wb[(ft * 2 + 1) * 512 + lane * 8];
            const float4 bv = *(const float4*)(ff1b + l * 2048 + c * 64 + ft * 16 + qc * 4);
            f32x4 c0; c0[0] = bv.x; c0[1] = bv.y; c0[2] = bv.z; c0[3] = bv.w;
            f32x4 c1 = c0;
            c0 = MFMA_B16(wa0, xb[0][0], c0); c0 = MFMA_B16(wa1, xb[0][1], c0);
            c1 = MFMA_B16(wa0, xb[1][0], c1); c1 = MFMA_B16(wa1, xb[1][1], c1);
            const int ha = ft >> 1, qa = (ft & 1) * 2 + (qc >> 1), jo = (qc & 1) * 4;
            const int boff = w * 2048 + ha * 512 + qa * 128 + m_ * 8 + jo;
            *(uint2*)&Act[boff] =
                make_uint2(pack2bf(fmaxf(c0[0], 0.f), fmaxf(c0[1], 0.f)),
                           pack2bf(fmaxf(c0[2], 0.f), fmaxf(c0[3], 0.f)));
            *(uint2*)&Act[boff + 1024] =
                make_uint2(pack2bf(fmaxf(c1[0], 0.f), fmaxf(c1[1], 0.f)),
                           pack2bf(fmaxf(c1[2], 0.f), fmaxf(c1[3], 0.f)));
        }
        bf16x8 ab[2][2];
        #pragma unroll
        for (int nt = 0; nt < 2; ++nt)
            #pragma unroll
            for (int h = 0; h < 2; ++h)
                ab[nt][h] = *(const bf16x8*)&Act[w * 2048 + (nt * 2 + h) * 512 + lane * 8];
        #pragma unroll
        for (int ot = 0; ot < 4; ++ot) {
            const bf16x8 w20 = *(const bf16x8*)&Wb[4096 + (ot * 2 + 0) * 512 + lane * 8];
            const bf16x8 w21 = *(const bf16x8*)&Wb[4096 + (ot * 2 + 1) * 512 + lane * 8];
            acc[ot][0] = MFMA_B16(w20, ab[0][0], acc[ot][0]);
            acc[ot][0] = MFMA_B16(w21, ab[0][1], acc[ot][0]);
            acc[ot][1] = MFMA_B16(w20, ab[1][0], acc[ot][1]);
            acc[ot][1] = MFMA_B16(w21, ab[1][1], acc[ot][1]);
        }
        __syncthreads();            // all reads of Wb chunk-c done
        if (c < 31) {
            *(uint4*)&Wb[t * 8] = p0;            *(uint4*)&Wb[(t + 256) * 8] = p1;
            *(uint4*)&Wb[4096 + t * 8] = p2;     *(uint4*)&Wb[4096 + (t + 256) * 8] = p3;
        }
    }

    float4 fb2v[4], gv[4], bv2[4];
    #pragma unroll
    for (int ot = 0; ot < 4; ++ot) {
        const int o = l * 64 + ot * 16 + qc * 4;
        fb2v[ot] = *(const float4*)(ff2b + o);
        gv[ot]   = *(const float4*)(ln2g + o);
        bv2[ot]  = *(const float4*)(ln2b + o);
    }
    #pragma unroll
    for (int nt = 0; nt < 2; ++nt) {
        const int tok = tok0 + w * 32 + nt * 16 + m_;
        const bool valid = tok < N_TOK;
        float v[4][4];
        float s = 0.f;
        #pragma unroll
        for (int ot = 0; ot < 4; ++ot) {
            float4 rs = make_float4(0.f, 0.f, 0.f, 0.f);
            if (valid) rs = *(const float4*)(e + tok * 64 + ot * 16 + qc * 4);
            v[ot][0] = acc[ot][nt][0] + fb2v[ot].x + rs.x;
            v[ot][1] = acc[ot][nt][1] + fb2v[ot].y + rs.y;
            v[ot][2] = acc[ot][nt][2] + fb2v[ot].z + rs.z;
            v[ot][3] = acc[ot][nt][3] + fb2v[ot].w + rs.w;
            s += v[ot][0] + v[ot][1] + v[ot][2] + v[ot][3];
        }
        s += __shfl_xor(s, 16); s += __shfl_xor(s, 32);
        const float mean = s * (1.f / 64.f);
        float vs = 0.f;
        #pragma unroll
        for (int ot = 0; ot < 4; ++ot)
            #pragma unroll
            for (int r = 0; r < 4; ++r) { v[ot][r] -= mean; vs += v[ot][r] * v[ot][r]; }
        vs += __shfl_xor(vs, 16); vs += __shfl_xor(vs, 32);
        const float rr = rsqrtf(vs * (1.f / 64.f) + LN_EPS);
        if (valid) {
            #pragma unroll
            for (int ot = 0; ot < 4; ++ot) {
                float4 o4 = make_float4(v[ot][0] * rr * gv[ot].x + bv2[ot].x,
                                        v[ot][1] * rr * gv[ot].y + bv2[ot].y,
                                        v[ot][2] * rr * gv[ot].z + bv2[ot].z,
                                        v[ot][3] * rr * gv[ot].w + bv2[ot].w);
                *(float4*)(eout + tok * 64 + ot * 16 + qc * 4) = o4;
            }
        }
    }
}

// ===================== Kernel 6: mean-pool + 2-layer regressor =====================
__global__ __launch_bounds__(256) void k_reg(
    const float* __restrict__ e,
    const float* __restrict__ r1w, const float* __restrict__ r1b,
    const float* __restrict__ r2w, const float* __restrict__ r2b,
    float* __restrict__ out)
{
    __shared__ float r1T[64][64];
    __shared__ float pld[4][64];
    const int t = threadIdx.x;
    #pragma unroll
    for (int i = 0; i < 4; ++i) {
        const int j  = (t & 15) + 16 * i;
        const int kq = t >> 4;
        const float4 v = *(const float4*)(r1w + j * 64 + kq * 4);
        r1T[kq * 4 + 0][j] = v.x; r1T[kq * 4 + 1][j] = v.y;
        r1T[kq * 4 + 2][j] = v.z; r1T[kq * 4 + 3][j] = v.w;
    }
    const int w = t >> 6, lane = t & 63;
    const int n = blockIdx.x * 4 + w;
    const float p = 0.25f * (e[(n * 4 + 0) * 64 + lane] + e[(n * 4 + 1) * 64 + lane] +
                             e[(n * 4 + 2) * 64 + lane] + e[(n * 4 + 3) * 64 + lane]);
    pld[w][lane] = p;
    __syncthreads();
    float acc = r1b[lane];
    #pragma unroll 8
    for (int k = 0; k < 64; ++k) acc += pld[w][k] * r1T[k][lane];
    acc = fmaxf(acc, 0.f);
    float partial = acc * r2w[lane];
    partial += __shfl_xor(partial, 1);  partial += __shfl_xor(partial, 2);
    partial += __shfl_xor(partial, 4);  partial += __shfl_xor(partial, 8);
    partial += __shfl_xor(partial, 16); partial += __shfl_xor(partial, 32);
    if (lane == 0) out[n] = partial + r2b[0];
}

// ===================== host launcher =====================
extern "C" void kernel_launch(void* const* d_in, const int* in_sizes, int n_in,
                              void* d_out, int out_size, void* d_ws, size_t ws_size,
                              hipStream_t stream) {
    const float* x    = (const float*)d_in[0];
    const int*   ei   = (const int*)d_in[1];
    const float* mpw  = (const float*)d_in[2];
    const float* W0   = (const float*)d_in[3];
    const float* b0   = (const float*)d_in[4];
    const float* Wl   = (const float*)d_in[5];
    const float* bl   = (const float*)d_in[6];
    const float* W1   = (const float*)d_in[7];
    const float* b1   = (const float*)d_in[8];
    const float* Wo   = (const float*)d_in[9];
    const float* bo   = (const float*)d_in[10];
    const float* tinw = (const float*)d_in[11];
    const float* tinb = (const float*)d_in[12];
    const float* tow  = (const float*)d_in[13];
    const float* tob  = (const float*)d_in[14];
    const float* ln1g = (const float*)d_in[15];
    const float* ln1b = (const float*)d_in[16];
    const float* ff1w = (const float*)d_in[17];
    const float* ff1b = (const float*)d_in[18];
    const float* ff2w = (const float*)d_in[19];
    const float* ff2b = (const float*)d_in[20];
    const float* ln2g = (const float*)d_in[21];
    const float* ln2b = (const float*)d_in[22];
    const float* r1w  = (const float*)d_in[23];
    const float* r1b  = (const float*)d_in[24];
    const float* r2w  = (const float*)d_in[25];
    const float* r2b  = (const float*)d_in[26];

    const size_t CH = (size_t)M_P * N_NODES * 64;
    float* y    = (float*)d_ws;
    float* zz   = y + CH;
    float* aggh = zz + CH;
    float* e    = aggh + CH;
    // y region is dead after k_gather — reuse for shuffled bf16 weights
    unsigned short* w1s    = (unsigned short*)y;
    unsigned short* w2s    = w1s + 262144;
    unsigned short* wqkv_s = w2s + 262144;
    unsigned short* tow_s  = wqkv_s + 24576;
    // e region is dead until k_emb — host the binning temporaries there
    int* cur                 = (int*)e;                         // N_ROWS cursors
    unsigned short* binned16 = (unsigned short*)(cur + N_ROWS); // N_ROWS*CAP ushorts (15.4 MB)

    hipMemsetAsync(cur, 0, N_ROWS * sizeof(int), stream);
    hipMemsetAsync(aggh, 0, CH * sizeof(float), stream);        // overflow-fallback accumulator
    k_lin_yz<<<dim3(469, 8), 256, 0, stream>>>(x, W0, b0, Wl, bl, W1, b1, y, zz);
    k_fill<<<(M_P * E_EDGES + 2047) / 2048, 256, 0, stream>>>(ei, cur, binned16, y, aggh);
    k_gather<<<N_ROWS / 4, 256, 0, stream>>>(cur, binned16, y, aggh);
    k_emb<<<N_NODES / 16, 256, 0, stream>>>(aggh, zz, Wo, bo, mpw, e);
    k_wshuf<<<1024, 256, 0, stream>>>(ff1w, ff2w, tinw, tow, w1s, w2s, wqkv_s, tow_s);
    for (int l = 0; l < 2; ++l) {
        k_attn_mfma<<<(N_TOK + 127) / 128, 256, 0, stream>>>(e, wqkv_s, tinb, tow_s, tob,
                                                             ln1g, ln1b, e, l);
        k_ffn_mfma<<<(N_TOK + 127) / 128, 256, 0, stream>>>(e, w1s, w2s, ff1b, ff2b,
                                                            ln2g, ln2b, e, l);
    }
    k_reg<<<N_NODES / 4, 256, 0, stream>>>(e, r1w, r1b, r2w, r2b, (float*)d_out);
}

// Round 7
// 707.759 us; speedup vs baseline: 1.7188x; 1.0820x over previous
//
#include <hip/hip_runtime.h>
#include <hip/hip_bf16.h>
#include <math.h>

#define N_NODES 30000
#define M_P     4
#define E_EDGES 480000
#define N_TOK   (N_NODES * 4)
#define N_ROWS  (M_P * N_NODES)      // 120000 (m,src) rows
#define SLOTS   62                   // per-row bin slots; row = 1×128B line: [int cnt | 62 ushort]
#define LN_EPS  1e-5f

typedef short bf16x8 __attribute__((ext_vector_type(8)));
typedef float f32x4  __attribute__((ext_vector_type(4)));
#define MFMA_B16(a, b, c) __builtin_amdgcn_mfma_f32_16x16x32_bf16(a, b, c, 0, 0, 0)

__device__ inline unsigned short f2bf(float f) {
    union { float f; unsigned u; } v; v.f = f;
    unsigned r = v.u + 0x7fffu + ((v.u >> 16) & 1u);
    return (unsigned short)(r >> 16);
}
// HW packed cvt (v_cvt_pk_bf16_f32, RNE — same rounding as f2bf)
__device__ inline unsigned pack2bf(float a, float b) {
    union { __hip_bfloat162 h; unsigned u; } cv;
    cv.h = __float22bfloat162_rn(make_float2(a, b));
    return cv.u;
}
__device__ inline float bf2f(short s) {
    union { unsigned u; float f; } v; v.u = ((unsigned)(unsigned short)s) << 16;
    return v.f;
}

// ===================== Kernel 1: y = x@Wl^T ; z = x@(W0+W1)^T + (b0+b1+bl) =====================
__global__ __launch_bounds__(256, 2) void k_lin_yz(
    const float* __restrict__ x,
    const float* __restrict__ W0, const float* __restrict__ b0,
    const float* __restrict__ Wl, const float* __restrict__ bl,
    const float* __restrict__ W1, const float* __restrict__ b1,
    float* __restrict__ y, float* __restrict__ z)
{
    __shared__ float xT[128][68];   // [k][node]
    __shared__ float wT[128][68];   // [k][h]
    const int t     = threadIdx.x;
    const int m     = blockIdx.y >> 1;
    const int which = blockIdx.y & 1;
    const int node0 = blockIdx.x * 64;

    #pragma unroll
    for (int i = 0; i < 8; ++i) {
        const int node = (t & 31) + 32 * (i & 1);
        const int kq   = (t >> 5) + 8 * (i >> 1);
        float4 v = make_float4(0.f, 0.f, 0.f, 0.f);
        const int n = node0 + node;
        if (n < N_NODES) v = *(const float4*)(x + n * 128 + kq * 4);
        xT[kq * 4 + 0][node] = v.x; xT[kq * 4 + 1][node] = v.y;
        xT[kq * 4 + 2][node] = v.z; xT[kq * 4 + 3][node] = v.w;
    }
    #pragma unroll
    for (int i = 0; i < 8; ++i) {
        const int h  = (t & 31) + 32 * (i & 1);
        const int kq = (t >> 5) + 8 * (i >> 1);
        float4 v;
        if (which) {
            v = *(const float4*)(W0 + (m * 64 + h) * 128 + kq * 4);
            const float4 v2 = *(const float4*)(W1 + (m * 64 + h) * 128 + kq * 4);
            v.x += v2.x; v.y += v2.y; v.z += v2.z; v.w += v2.w;
        } else {
            v = *(const float4*)(Wl + (m * 64 + h) * 128 + kq * 4);
        }
        wT[kq * 4 + 0][h] = v.x; wT[kq * 4 + 1][h] = v.y;
        wT[kq * 4 + 2][h] = v.z; wT[kq * 4 + 3][h] = v.w;
    }
    __syncthreads();

    const int tx = t & 15, ty = t >> 4;
    const int hb = tx * 4, nb = ty * 4;
    float acc[4][4] = {};
    #pragma unroll 8
    for (int k = 0; k < 128; ++k) {
        const float4 a = *(const float4*)&xT[k][nb];
        const float4 b = *(const float4*)&wT[k][hb];
        acc[0][0] += a.x * b.x; acc[0][1] += a.x * b.y; acc[0][2] += a.x * b.z; acc[0][3] += a.x * b.w;
        acc[1][0] += a.y * b.x; acc[1][1] += a.y * b.y; acc[1][2] += a.y * b.z; acc[1][3] += a.y * b.w;
        acc[2][0] += a.z * b.x; acc[2][1] += a.z * b.y; acc[2][2] += a.z * b.z; acc[2][3] += a.z * b.w;
        acc[3][0] += a.w * b.x; acc[3][1] += a.w * b.y; acc[3][2] += a.w * b.z; acc[3][3] += a.w * b.w;
    }
    float bias[4] = {0.f, 0.f, 0.f, 0.f};
    if (which) {
        #pragma unroll
        for (int j = 0; j < 4; ++j)
            bias[j] = b0[m * 64 + hb + j] + b1[m * 64 + hb + j] + bl[m * 64 + hb + j];
    }
    float* outp = which ? z : y;
    #pragma unroll
    for (int i = 0; i < 4; ++i) {
        const int n = node0 + nb + i;
        if (n < N_NODES) {
            float4 v = make_float4(acc[i][0] + bias[0], acc[i][1] + bias[1],
                                   acc[i][2] + bias[2], acc[i][3] + bias[3]);
            *(float4*)(outp + (m * N_NODES + n) * 64 + hb) = v;
        }
    }
}

// ===================== Single-line bins: [int cnt | 62 ushort dst] per row (128 B = 1 L2 line) ==========
// Atomic cursor and slot store hit the SAME cache line. 4 edges/thread for grid size.
__global__ __launch_bounds__(256) void k_fill(
    const int* __restrict__ ei, unsigned short* __restrict__ bins,
    const float* __restrict__ y, float* __restrict__ aggh)
{
    const int base = blockIdx.x * 1024 + threadIdx.x;   // grid covers exactly M*E
    int rows[4], dsts[4];
    #pragma unroll
    for (int i = 0; i < 4; ++i) {
        const int g = base + i * 256;                   // coalesced per i
        const int m = g / E_EDGES;
        const int e = g - m * E_EDGES;
        rows[i] = m * N_NODES + ei[(m * 2) * E_EDGES + e];
        dsts[i] = ei[(m * 2 + 1) * E_EDGES + e];
    }
    int pos[4];
    #pragma unroll
    for (int i = 0; i < 4; ++i)
        pos[i] = atomicAdd((int*)bins + rows[i] * 32, 1);    // header int of the bin line
    #pragma unroll
    for (int i = 0; i < 4; ++i) {
        if (pos[i] < SLOTS) {
            bins[rows[i] * 64 + 2 + pos[i]] = (unsigned short)dsts[i];  // same 128 B line
        } else {                                        // safety net, statistically never taken
            const int m = rows[i] / N_NODES;
            const float* yr = y + ((size_t)m * N_NODES + dsts[i]) * 64;
            for (int f = 0; f < 64; ++f)
                unsafeAtomicAdd(&aggh[(size_t)rows[i] * 64 + f], yr[f]);
        }
    }
}

// Gather-reduce — one wave per (m,src) row; lane = feature. One 128 B slab read per row.
__global__ __launch_bounds__(256) void k_gather(
    const unsigned short* __restrict__ bins,
    const float* __restrict__ y, float* __restrict__ aggh)
{
    const int w = threadIdx.x >> 6, lane = threadIdx.x & 63;
    const int row = blockIdx.x * 4 + w;                 // < N_ROWS
    const int m = row / N_NODES;
    const float* ym = y + (size_t)m * N_NODES * 64;
    const int v = bins[row * 64 + lane];                // lanes 0,1 hold the header halves
    const int v0 = __shfl(v, 0), v1 = __shfl(v, 1);
    const int tot = (v0 & 0xffff) | (v1 << 16);
    const int cnt = min(tot, SLOTS);
    float acc = (tot > SLOTS) ? aggh[(size_t)row * 64 + lane] : 0.f;  // overflow contributions
    for (int j = 0; j < cnt; ++j) {
        const int r = __shfl(v, j + 2);                 // broadcast dst from slot lane
        acc += ym[r * 64 + lane];                       // 256 B contiguous, L3-resident
    }
    aggh[(size_t)row * 64 + lane] = acc;
}

// ===================== Kernel 3: e[n][m][:] = (relu(aggh+z) @ Wo^T + bo) * mpw[m] =====================
__global__ __launch_bounds__(256) void k_emb(
    const float* __restrict__ aggh, const float* __restrict__ z,
    const float* __restrict__ Wo, const float* __restrict__ bo,
    const float* __restrict__ mpw, float* __restrict__ e)
{
    __shared__ float hT[64][20];
    __shared__ float WoT[64][64];
    const int t = threadIdx.x;
    const int node0 = blockIdx.x * 16;

    for (int m = 0; m < 4; ++m) {
        #pragma unroll
        for (int i = 0; i < 4; ++i) {
            const int o  = (t & 15) + 16 * i;
            const int kq = t >> 4;
            const float4 v = *(const float4*)(Wo + (m * 64 + o) * 64 + kq * 4);
            WoT[kq * 4 + 0][o] = v.x; WoT[kq * 4 + 1][o] = v.y;
            WoT[kq * 4 + 2][o] = v.z; WoT[kq * 4 + 3][o] = v.w;
        }
        {
            const int node = t & 15, kq = t >> 4;
            const int n = node0 + node;
            const float4 a = *(const float4*)(aggh + (m * N_NODES + n) * 64 + kq * 4);
            const float4 b = *(const float4*)(z + (m * N_NODES + n) * 64 + kq * 4);
            hT[kq * 4 + 0][node] = fmaxf(a.x + b.x, 0.f);
            hT[kq * 4 + 1][node] = fmaxf(a.y + b.y, 0.f);
            hT[kq * 4 + 2][node] = fmaxf(a.z + b.z, 0.f);
            hT[kq * 4 + 3][node] = fmaxf(a.w + b.w, 0.f);
        }
        __syncthreads();
        const int o = t & 63, nl4 = (t >> 6) * 4;
        float acc[4] = {};
        #pragma unroll 8
        for (int k = 0; k < 64; ++k) {
            const float bw = WoT[k][o];
            const float4 a = *(const float4*)&hT[k][nl4];
            acc[0] += a.x * bw; acc[1] += a.y * bw; acc[2] += a.z * bw; acc[3] += a.w * bw;
        }
        const float bb = bo[m * 64 + o];
        const float w  = mpw[m];
        #pragma unroll
        for (int i = 0; i < 4; ++i)
            e[((node0 + nl4 + i) * 4 + m) * 64 + o] = (acc[i] + bb) * w;
        __syncthreads();
    }
}

// ===================== Kernel 4: attention via bf16 MFMA (no barriers, per-wave LDS) =====================
__global__ __launch_bounds__(256, 2) void k_attn_mfma(
    const float* __restrict__ e,
    const unsigned short* __restrict__ wqkv_s, const float* __restrict__ tinb,
    const unsigned short* __restrict__ tow_s, const float* __restrict__ tob,
    const float* __restrict__ ln1g, const float* __restrict__ ln1b,
    float* __restrict__ eout, int l)
{
    __shared__ __align__(16) short Xl[8192];      // 16 KB [w][2048]: X B-frags, then O B-frags
    __shared__ __align__(16) short QKV[25600];    // 50 KB [w][tok(32)][200]
    const int t = threadIdx.x;
    const int w = t >> 6, lane = t & 63;
    const int m_ = lane & 15, qc = lane >> 4;
    const int tok0 = blockIdx.x * 128;
    short* Xw = &Xl[w * 2048];
    short* Qw = &QKV[w * 6400];

    #pragma unroll
    for (int i = 0; i < 4; ++i) {
        const int rem = lane + 64 * i;
        const int nt = rem >> 7, h = (rem >> 6) & 1, q = (rem >> 4) & 3, n = rem & 15;
        const int tok = tok0 + w * 32 + nt * 16 + n;
        const int k0 = h * 32 + q * 8;
        float4 a = make_float4(0.f, 0.f, 0.f, 0.f), b = a;
        if (tok < N_TOK) {
            a = *(const float4*)(e + tok * 64 + k0);
            b = *(const float4*)(e + tok * 64 + k0 + 4);
        }
        *(uint4*)&Xw[rem * 8] = make_uint4(pack2bf(a.x, a.y), pack2bf(a.z, a.w),
                                           pack2bf(b.x, b.y), pack2bf(b.z, b.w));
    }

    bf16x8 xb[2][2];
    #pragma unroll
    for (int nt = 0; nt < 2; ++nt)
        #pragma unroll
        for (int h = 0; h < 2; ++h)
            xb[nt][h] = *(const bf16x8*)&Xw[(nt * 2 + h) * 512 + lane * 8];

    const unsigned short* Wq = wqkv_s + l * 12288;
    f32x4 acc[12][2];
    #pragma unroll
    for (int ft = 0; ft < 12; ++ft) {
        const bf16x8 wa0 = *(const bf16x8*)(Wq + (ft * 2 + 0) * 512 + lane * 8);
        const bf16x8 wa1 = *(const bf16x8*)(Wq + (ft * 2 + 1) * 512 + lane * 8);
        const float4 bv = *(const float4*)(tinb + l * 192 + ft * 16 + qc * 4);
        f32x4 c0; c0[0] = bv.x; c0[1] = bv.y; c0[2] = bv.z; c0[3] = bv.w;
        f32x4 c1 = c0;
        c0 = MFMA_B16(wa0, xb[0][0], c0); c0 = MFMA_B16(wa1, xb[0][1], c0);
        c1 = MFMA_B16(wa0, xb[1][0], c1); c1 = MFMA_B16(wa1, xb[1][1], c1);
        acc[ft][0] = c0; acc[ft][1] = c1;
    }
    #pragma unroll
    for (int ft = 0; ft < 12; ++ft)
        #pragma unroll
        for (int nt = 0; nt < 2; ++nt) {
            const int addr = (nt * 16 + m_) * 200 + ft * 16 + qc * 4;
            *(uint2*)&Qw[addr] = make_uint2(pack2bf(acc[ft][nt][0], acc[ft][nt][1]),
                                            pack2bf(acc[ft][nt][2], acc[ft][nt][3]));
        }

    {
        const int node = lane >> 3, head = lane & 7;
        float kk[4][8], vv[4][8];
        #pragma unroll
        for (int j2 = 0; j2 < 4; ++j2) {
            const bf16x8 kr = *(const bf16x8*)&Qw[(node * 4 + j2) * 200 + 64 + head * 8];
            const bf16x8 vr = *(const bf16x8*)&Qw[(node * 4 + j2) * 200 + 128 + head * 8];
            #pragma unroll
            for (int d = 0; d < 8; ++d) { kk[j2][d] = bf2f(kr[d]); vv[j2][d] = bf2f(vr[d]); }
        }
        const float scale = 0.35355339059327373f;
        const int nt = node >> 2, hq = head >> 2, qq = head & 3;
        #pragma unroll
        for (int i = 0; i < 4; ++i) {
            const bf16x8 qr = *(const bf16x8*)&Qw[(node * 4 + i) * 200 + head * 8];
            float q[8];
            #pragma unroll
            for (int d = 0; d < 8; ++d) q[d] = bf2f(qr[d]);
            float s[4];
            #pragma unroll
            for (int j2 = 0; j2 < 4; ++j2) {
                float a2 = 0.f;
                #pragma unroll
                for (int d = 0; d < 8; ++d) a2 += q[d] * kk[j2][d];
                s[j2] = a2 * scale;
            }
            const float mx = fmaxf(fmaxf(s[0], s[1]), fmaxf(s[2], s[3]));
            float p[4], sum = 0.f;
            #pragma unroll
            for (int j2 = 0; j2 < 4; ++j2) { p[j2] = __expf(s[j2] - mx); sum += p[j2]; }
            const float inv = 1.f / sum;
            float o[8];
            #pragma unroll
            for (int d = 0; d < 8; ++d)
                o[d] = (p[0] * vv[0][d] + p[1] * vv[1][d] + p[2] * vv[2][d] + p[3] * vv[3][d]) * inv;
            const int n = (node & 3) * 4 + i;
            *(uint4*)&Xw[(nt * 2 + hq) * 512 + qq * 128 + n * 8] =
                make_uint4(pack2bf(o[0], o[1]), pack2bf(o[2], o[3]),
                           pack2bf(o[4], o[5]), pack2bf(o[6], o[7]));
        }
    }

    bf16x8 ob[2][2];
    #pragma unroll
    for (int nt = 0; nt < 2; ++nt)
        #pragma unroll
        for (int h = 0; h < 2; ++h)
            ob[nt][h] = *(const bf16x8*)&Xw[(nt * 2 + h) * 512 + lane * 8];
    const unsigned short* Tw = tow_s + l * 4096;
    f32x4 acc2[4][2] = {};
    #pragma unroll
    for (int ot = 0; ot < 4; ++ot) {
        const bf16x8 t0 = *(const bf16x8*)(Tw + (ot * 2 + 0) * 512 + lane * 8);
        const bf16x8 t1 = *(const bf16x8*)(Tw + (ot * 2 + 1) * 512 + lane * 8);
        acc2[ot][0] = MFMA_B16(t0, ob[0][0], acc2[ot][0]);
        acc2[ot][0] = MFMA_B16(t1, ob[0][1], acc2[ot][0]);
        acc2[ot][1] = MFMA_B16(t0, ob[1][0], acc2[ot][1]);
        acc2[ot][1] = MFMA_B16(t1, ob[1][1], acc2[ot][1]);
    }

    float4 tbv[4], gv[4], bv2[4];
    #pragma unroll
    for (int ot = 0; ot < 4; ++ot) {
        const int o = l * 64 + ot * 16 + qc * 4;
        tbv[ot] = *(const float4*)(tob + o);
        gv[ot]  = *(const float4*)(ln1g + o);
        bv2[ot] = *(const float4*)(ln1b + o);
    }
    #pragma unroll
    for (int nt = 0; nt < 2; ++nt) {
        const int tok = tok0 + w * 32 + nt * 16 + m_;
        const bool valid = tok < N_TOK;
        float v[4][4];
        float s = 0.f;
        #pragma unroll
        for (int ot = 0; ot < 4; ++ot) {
            float4 rs = make_float4(0.f, 0.f, 0.f, 0.f);
            if (valid) rs = *(const float4*)(e + tok * 64 + ot * 16 + qc * 4);
            v[ot][0] = acc2[ot][nt][0] + tbv[ot].x + rs.x;
            v[ot][1] = acc2[ot][nt][1] + tbv[ot].y + rs.y;
            v[ot][2] = acc2[ot][nt][2] + tbv[ot].z + rs.z;
            v[ot][3] = acc2[ot][nt][3] + tbv[ot].w + rs.w;
            s += v[ot][0] + v[ot][1] + v[ot][2] + v[ot][3];
        }
        s += __shfl_xor(s, 16); s += __shfl_xor(s, 32);
        const float mean = s * (1.f / 64.f);
        float vs = 0.f;
        #pragma unroll
        for (int ot = 0; ot < 4; ++ot)
            #pragma unroll
            for (int r = 0; r < 4; ++r) { v[ot][r] -= mean; vs += v[ot][r] * v[ot][r]; }
        vs += __shfl_xor(vs, 16); vs += __shfl_xor(vs, 32);
        const float rr = rsqrtf(vs * (1.f / 64.f) + LN_EPS);
        if (valid) {
            #pragma unroll
            for (int ot = 0; ot < 4; ++ot) {
                float4 o4 = make_float4(v[ot][0] * rr * gv[ot].x + bv2[ot].x,
                                        v[ot][1] * rr * gv[ot].y + bv2[ot].y,
                                        v[ot][2] * rr * gv[ot].z + bv2[ot].z,
                                        v[ot][3] * rr * gv[ot].w + bv2[ot].w);
                *(float4*)(eout + tok * 64 + ot * 16 + qc * 4) = o4;
            }
        }
    }
}

// ===================== Kernel 4.5: pre-shuffle weights to MFMA-fragment-major bf16 =====================
__global__ __launch_bounds__(256) void k_wshuf(
    const float* __restrict__ ff1w, const float* __restrict__ ff2w,
    const float* __restrict__ tinw, const float* __restrict__ tow,
    unsigned short* __restrict__ w1s, unsigned short* __restrict__ w2s,
    unsigned short* __restrict__ wqkv_s, unsigned short* __restrict__ tow_s)
{
    const int g = blockIdx.x * 256 + threadIdx.x;   // [0, 262144)
    {
        const int l = g >> 17, r2 = g & 131071;
        const int f = r2 >> 6, k = r2 & 63;
        const int c = f >> 6, fc = f & 63, ft = fc >> 4, m = fc & 15;
        const int h = k >> 5, q = (k >> 3) & 3, j = k & 7;
        w1s[l * 131072 + c * 4096 + (ft * 2 + h) * 512 + (q * 16 + m) * 8 + j] = f2bf(ff1w[g]);
    }
    {
        const int l = g >> 17, r2 = g & 131071;
        const int o = r2 >> 11, f = r2 & 2047;
        const int c = f >> 6, fc = f & 63, h = fc >> 5, q = (fc >> 3) & 3, j = fc & 7;
        const int ot = o >> 4, m = o & 15;
        w2s[l * 131072 + c * 4096 + (ot * 2 + h) * 512 + (q * 16 + m) * 8 + j] = f2bf(ff2w[g]);
    }
    if (g < 2 * 192 * 64) {        // qkv in_proj: A-frag, M=f(192), K=64
        const int l = g / 12288, r2 = g - l * 12288;
        const int f = r2 >> 6, k = r2 & 63;
        const int ft = f >> 4, m = f & 15;
        const int h = k >> 5, q = (k >> 3) & 3, j = k & 7;
        wqkv_s[l * 12288 + (ft * 2 + h) * 512 + (q * 16 + m) * 8 + j] = f2bf(tinw[g]);
    }
    if (g < 2 * 64 * 64) {         // out_proj: A-frag, M=o(64), K=64
        const int l = g >> 12, r2 = g & 4095;
        const int o = r2 >> 6, k = r2 & 63;
        const int ot = o >> 4, m = o & 15;
        const int h = k >> 5, q = (k >> 3) & 3, j = k & 7;
        tow_s[l * 4096 + (ot * 2 + h) * 512 + (q * 16 + m) * 8 + j] = f2bf(tow[g]);
    }
}

// ===================== Kernel 5: FFN via bf16 MFMA, single-buffer weights (48 KB LDS, 3 blk/CU) ==========
__global__ __launch_bounds__(256, 3) void k_ffn_mfma(
    const float* __restrict__ e,
    const unsigned short* __restrict__ w1s, const unsigned short* __restrict__ w2s,
    const float* __restrict__ ff1b, const float* __restrict__ ff2b,
    const float* __restrict__ ln2g, const float* __restrict__ ln2b,
    float* __restrict__ eout, int l)
{
    __shared__ __align__(16) short Xl[8192];     // 16 KB
    __shared__ __align__(16) short Act[8192];    // 16 KB
    __shared__ __align__(16) short Wb[8192];     // 16 KB [ W1 4096 | W2 4096 ]
    const int t = threadIdx.x;
    const int w = t >> 6, lane = t & 63;
    const int m_ = lane & 15, qc = lane >> 4;
    const int tok0 = blockIdx.x * 128;

    #pragma unroll
    for (int i = 0; i < 4; ++i) {
        const int g = t + 256 * i;
        const int gw = g >> 8, rem = g & 255;
        const int nt = rem >> 7, h = (rem >> 6) & 1, q = (rem >> 4) & 3, n = rem & 15;
        const int tok = tok0 + gw * 32 + nt * 16 + n;
        const int k = h * 32 + q * 8;
        float4 a = make_float4(0.f, 0.f, 0.f, 0.f), b = a;
        if (tok < N_TOK) {
            a = *(const float4*)(e + tok * 64 + k);
            b = *(const float4*)(e + tok * 64 + k + 4);
        }
        *(uint4*)&Xl[g * 8] = make_uint4(pack2bf(a.x, a.y), pack2bf(a.z, a.w),
                                         pack2bf(b.x, b.y), pack2bf(b.z, b.w));
    }

    const uint4* gw1 = (const uint4*)(w1s + l * 131072);
    const uint4* gw2 = (const uint4*)(w2s + l * 131072);
    uint4 p0 = gw1[t], p1 = gw1[t + 256], p2 = gw2[t], p3 = gw2[t + 256];
    *(uint4*)&Wb[t * 8] = p0;            *(uint4*)&Wb[(t + 256) * 8] = p1;
    *(uint4*)&Wb[4096 + t * 8] = p2;     *(uint4*)&Wb[4096 + (t + 256) * 8] = p3;

    f32x4 acc[4][2] = {};

    for (int c = 0; c < 32; ++c) {
        __syncthreads();            // Wb chunk-c visible
        if (c < 31) {               // issue next chunk's global loads (in flight across compute)
            p0 = gw1[(c + 1) * 512 + t];       p1 = gw1[(c + 1) * 512 + t + 256];
            p2 = gw2[(c + 1) * 512 + t];       p3 = gw2[(c + 1) * 512 + t + 256];
        }
        bf16x8 xb[2][2];
        #pragma unroll
        for (int nt = 0; nt < 2; ++nt)
            #pragma unroll
            for (int h = 0; h < 2; ++h)
                xb[nt][h] = *(const bf16x8*)&Xl[w * 2048 + (nt * 2 + h) * 512 + lane * 8];

        #pragma unroll
        for (int ft = 0; ft < 4; ++ft) {
            const bf16x8 wa0 = *(const bf16x8*)&Wb[(ft * 2 + 0) * 512 + lane * 8];
            const bf16x8 wa1 = *(const bf16x8*)&Wb[(ft * 2 + 1) * 512 + lane * 8];
            const float4 bv = *(const float4*)(ff1b + l * 2048 + c * 64 + ft * 16 + qc * 4);
            f32x4 c0; c0[0] = bv.x; c0[1] = bv.y; c0[2] = bv.z; c0[3] = bv.w;
            f32x4 c1 = c0;
            c0 = MFMA_B16(wa0, xb[0][0], c0); c0 = MFMA_B16(wa1, xb[0][1], c0);
            c1 = MFMA_B16(wa0, xb[1][0], c1); c1 = MFMA_B16(wa1, xb[1][1], c1);
            const int ha = ft >> 1, qa = (ft & 1) * 2 + (qc >> 1), jo = (qc & 1) * 4;
            const int boff = w * 2048 + ha * 512 + qa * 128 + m_ * 8 + jo;
            *(uint2*)&Act[boff] =
                make_uint2(pack2bf(fmaxf(c0[0], 0.f), fmaxf(c0[1], 0.f)),
                           pack2bf(fmaxf(c0[2], 0.f), fmaxf(c0[3], 0.f)));
            *(uint2*)&Act[boff + 1024] =
                make_uint2(pack2bf(fmaxf(c1[0], 0.f), fmaxf(c1[1], 0.f)),
                           pack2bf(fmaxf(c1[2], 0.f), fmaxf(c1[3], 0.f)));
        }
        bf16x8 ab[2][2];
        #pragma unroll
        for (int nt = 0; nt < 2; ++nt)
            #pragma unroll
            for (int h = 0; h < 2; ++h)
                ab[nt][h] = *(const bf16x8*)&Act[w * 2048 + (nt * 2 + h) * 512 + lane * 8];
        #pragma unroll
        for (int ot = 0; ot < 4; ++ot) {
            const bf16x8 w20 = *(const bf16x8*)&Wb[4096 + (ot * 2 + 0) * 512 + lane * 8];
            const bf16x8 w21 = *(const bf16x8*)&Wb[4096 + (ot * 2 + 1) * 512 + lane * 8];
            acc[ot][0] = MFMA_B16(w20, ab[0][0], acc[ot][0]);
            acc[ot][0] = MFMA_B16(w21, ab[0][1], acc[ot][0]);
            acc[ot][1] = MFMA_B16(w20, ab[1][0], acc[ot][1]);
            acc[ot][1] = MFMA_B16(w21, ab[1][1], acc[ot][1]);
        }
        __syncthreads();            // all reads of Wb chunk-c done
        if (c < 31) {
            *(uint4*)&Wb[t * 8] = p0;            *(uint4*)&Wb[(t + 256) * 8] = p1;
            *(uint4*)&Wb[4096 + t * 8] = p2;     *(uint4*)&Wb[4096 + (t + 256) * 8] = p3;
        }
    }

    float4 fb2v[4], gv[4], bv2[4];
    #pragma unroll
    for (int ot = 0; ot < 4; ++ot) {
        const int o = l * 64 + ot * 16 + qc * 4;
        fb2v[ot] = *(const float4*)(ff2b + o);
        gv[ot]   = *(const float4*)(ln2g + o);
        bv2[ot]  = *(const float4*)(ln2b + o);
    }
    #pragma unroll
    for (int nt = 0; nt < 2; ++nt) {
        const int tok = tok0 + w * 32 + nt * 16 + m_;
        const bool valid = tok < N_TOK;
        float v[4][4];
        float s = 0.f;
        #pragma unroll
        for (int ot = 0; ot < 4; ++ot) {
            float4 rs = make_float4(0.f, 0.f, 0.f, 0.f);
            if (valid) rs = *(const float4*)(e + tok * 64 + ot * 16 + qc * 4);
            v[ot][0] = acc[ot][nt][0] + fb2v[ot].x + rs.x;
            v[ot][1] = acc[ot][nt][1] + fb2v[ot].y + rs.y;
            v[ot][2] = acc[ot][nt][2] + fb2v[ot].z + rs.z;
            v[ot][3] = acc[ot][nt][3] + fb2v[ot].w + rs.w;
            s += v[ot][0] + v[ot][1] + v[ot][2] + v[ot][3];
        }
        s += __shfl_xor(s, 16); s += __shfl_xor(s, 32);
        const float mean = s * (1.f / 64.f);
        float vs = 0.f;
        #pragma unroll
        for (int ot = 0; ot < 4; ++ot)
            #pragma unroll
            for (int r = 0; r < 4; ++r) { v[ot][r] -= mean; vs += v[ot][r] * v[ot][r]; }
        vs += __shfl_xor(vs, 16); vs += __shfl_xor(vs, 32);
        const float rr = rsqrtf(vs * (1.f / 64.f) + LN_EPS);
        if (valid) {
            #pragma unroll
            for (int ot = 0; ot < 4; ++ot) {
                float4 o4 = make_float4(v[ot][0] * rr * gv[ot].x + bv2[ot].x,
                                        v[ot][1] * rr * gv[ot].y + bv2[ot].y,
                                        v[ot][2] * rr * gv[ot].z + bv2[ot].z,
                                        v[ot][3] * rr * gv[ot].w + bv2[ot].w);
                *(float4*)(eout + tok * 64 + ot * 16 + qc * 4) = o4;
            }
        }
    }
}

// ===================== Kernel 6: mean-pool + 2-layer regressor =====================
__global__ __launch_bounds__(256) void k_reg(
    const float* __restrict__ e,
    const float* __restrict__ r1w, const float* __restrict__ r1b,
    const float* __restrict__ r2w, const float* __restrict__ r2b,
    float* __restrict__ out)
{
    __shared__ float r1T[64][64];
    __shared__ float pld[4][64];
    const int t = threadIdx.x;
    #pragma unroll
    for (int i = 0; i < 4; ++i) {
        const int j  = (t & 15) + 16 * i;
        const int kq = t >> 4;
        const float4 v = *(const float4*)(r1w + j * 64 + kq * 4);
        r1T[kq * 4 + 0][j] = v.x; r1T[kq * 4 + 1][j] = v.y;
        r1T[kq * 4 + 2][j] = v.z; r1T[kq * 4 + 3][j] = v.w;
    }
    const int w = t >> 6, lane = t & 63;
    const int n = blockIdx.x * 4 + w;
    const float p = 0.25f * (e[(n * 4 + 0) * 64 + lane] + e[(n * 4 + 1) * 64 + lane] +
                             e[(n * 4 + 2) * 64 + lane] + e[(n * 4 + 3) * 64 + lane]);
    pld[w][lane] = p;
    __syncthreads();
    float acc = r1b[lane];
    #pragma unroll 8
    for (int k = 0; k < 64; ++k) acc += pld[w][k] * r1T[k][lane];
    acc = fmaxf(acc, 0.f);
    float partial = acc * r2w[lane];
    partial += __shfl_xor(partial, 1);  partial += __shfl_xor(partial, 2);
    partial += __shfl_xor(partial, 4);  partial += __shfl_xor(partial, 8);
    partial += __shfl_xor(partial, 16); partial += __shfl_xor(partial, 32);
    if (lane == 0) out[n] = partial + r2b[0];
}

// ===================== host launcher =====================
extern "C" void kernel_launch(void* const* d_in, const int* in_sizes, int n_in,
                              void* d_out, int out_size, void* d_ws, size_t ws_size,
                              hipStream_t stream) {
    const float* x    = (const float*)d_in[0];
    const int*   ei   = (const int*)d_in[1];
    const float* mpw  = (const float*)d_in[2];
    const float* W0   = (const float*)d_in[3];
    const float* b0   = (const float*)d_in[4];
    const float* Wl   = (const float*)d_in[5];
    const float* bl   = (const float*)d_in[6];
    const float* W1   = (const float*)d_in[7];
    const float* b1   = (const float*)d_in[8];
    const float* Wo   = (const float*)d_in[9];
    const float* bo   = (const float*)d_in[10];
    const float* tinw = (const float*)d_in[11];
    const float* tinb = (const float*)d_in[12];
    const float* tow  = (const float*)d_in[13];
    const float* tob  = (const float*)d_in[14];
    const float* ln1g = (const float*)d_in[15];
    const float* ln1b = (const float*)d_in[16];
    const float* ff1w = (const float*)d_in[17];
    const float* ff1b = (const float*)d_in[18];
    const float* ff2w = (const float*)d_in[19];
    const float* ff2b = (const float*)d_in[20];
    const float* ln2g = (const float*)d_in[21];
    const float* ln2b = (const float*)d_in[22];
    const float* r1w  = (const float*)d_in[23];
    const float* r1b  = (const float*)d_in[24];
    const float* r2w  = (const float*)d_in[25];
    const float* r2b  = (const float*)d_in[26];

    const size_t CH = (size_t)M_P * N_NODES * 64;
    float* y    = (float*)d_ws;
    float* zz   = y + CH;
    float* aggh = zz + CH;
    float* e    = aggh + CH;
    // y region is dead after k_gather — reuse for shuffled bf16 weights
    unsigned short* w1s    = (unsigned short*)y;
    unsigned short* w2s    = w1s + 262144;
    unsigned short* wqkv_s = w2s + 262144;
    unsigned short* tow_s  = wqkv_s + 24576;
    // e region is dead until k_emb — host the bin lines there (120000 × 128 B = 15.36 MB)
    unsigned short* bins = (unsigned short*)e;

    hipMemsetAsync(bins, 0, (size_t)N_ROWS * 128, stream);      // clear headers (+slots)
    hipMemsetAsync(aggh, 0, CH * sizeof(float), stream);        // overflow-fallback accumulator
    k_lin_yz<<<dim3(469, 8), 256, 0, stream>>>(x, W0, b0, Wl, bl, W1, b1, y, zz);
    k_fill<<<(M_P * E_EDGES) / 1024, 256, 0, stream>>>(ei, bins, y, aggh);
    k_gather<<<N_ROWS / 4, 256, 0, stream>>>(bins, y, aggh);
    k_emb<<<N_NODES / 16, 256, 0, stream>>>(aggh, zz, Wo, bo, mpw, e);
    k_wshuf<<<1024, 256, 0, stream>>>(ff1w, ff2w, tinw, tow, w1s, w2s, wqkv_s, tow_s);
    for (int l = 0; l < 2; ++l) {
        k_attn_mfma<<<(N_TOK + 127) / 128, 256, 0, stream>>>(e, wqkv_s, tinb, tow_s, tob,
                                                             ln1g, ln1b, e, l);
        k_ffn_mfma<<<(N_TOK + 127) / 128, 256, 0, stream>>>(e, w1s, w2s, ff1b, ff2b,
                                                            ln2g, ln2b, e, l);
    }
    k_reg<<<N_NODES / 4, 256, 0, stream>>>(e, r1w, r1b, r2w, r2b, (float*)d_out);
}